// Round 5
// baseline (282.922 us; speedup 1.0000x reference)
//
#include <hip/hip_runtime.h>

// B=4, T=2048, D=1024, H=16, hd=64. Inputs/output fp32; internal bf16 MFMA.
// R15: (a) revert R14's qt permutation (cost 4us: VGPR 76->80, occ 28->26,
// no makespan gain -> dispatch model wrong). attn == verified R12 (79.8us).
// (b) gemm1 -> 256x256 8-phase counted-vmcnt kernel (T3+T4+T5, no swizzle
// yet): 512 thr / 8 waves (2Mx4N), BK=64, 128KB LDS dbuf, per-tile 4 phases
// {stage 1 half-tile, barrier, quadrant MFMA x16, barrier}, vmcnt(8) keeps
// 4 half-tiles permanently in flight (never drains). Stage order per tile t:
// p1:B1(t+1) p2:A1(t+1) p3:B0(t+2) p4:A0(t+2) — each region staged only
// after the barrier following its last reader (WAR-safe by construction).
// gemm2 stays on the verified 128^2 path (control).

typedef __bf16 bf16;
typedef __attribute__((ext_vector_type(8))) __bf16 bf16x8;
typedef __attribute__((ext_vector_type(4))) __bf16 bf16x4;
typedef __attribute__((ext_vector_type(4))) float f4;

#define BK 32

__device__ __forceinline__ void stage16(const bf16* g, bf16* l) {
    __builtin_amdgcn_global_load_lds((const __attribute__((address_space(1))) void*)g,
                                     (__attribute__((address_space(3))) void*)l,
                                     16, 0, 0);
}

// ---------------- cast fp32 -> bf16, vectorized ---------------------------
__global__ __launch_bounds__(256)
void cast_f32_bf16(const float* __restrict__ src, bf16* __restrict__ dst, int n4)
{
    int i = blockIdx.x * 256 + threadIdx.x;
    if (i < n4) {
        float4 v = ((const float4*)src)[i];
        bf16x4 o = { (bf16)v.x, (bf16)v.y, (bf16)v.z, (bf16)v.w };
        *(bf16x4*)&dst[i * 4] = o;
    }
}

// ---------------- transpose + cast: fp32 src [R][C] -> bf16 dst [C][R] ----
__global__ __launch_bounds__(256)
void transpose_f32_bf16(const float* __restrict__ src, bf16* __restrict__ dst,
                        int R, int C)
{
    __shared__ bf16 tile[64][65];
    int c0 = blockIdx.x * 64, r0 = blockIdx.y * 64;
    int tid = threadIdx.x;
    for (int i = tid; i < 64 * 64; i += 256) {
        int r = i >> 6, c = i & 63;
        tile[r][c] = (bf16)src[(long)(r0 + r) * C + c0 + c];
    }
    __syncthreads();
    for (int i = tid; i < 64 * 64; i += 256) {
        int r = i >> 6, c = i & 63;
        dst[(long)(c0 + r) * R + r0 + c] = tile[c][r];
    }
}

// ---------------- GEMM: C[M,N] = A[M,K] x Bt[N,K]^T, bf16 in, OutT out ----
// 128x128 tile, BK=32, global_load_lds width-16 staging (m97 pattern).
// + T1 XCD-aware block swizzle (requires nwg % 8 == 0; holds: 512).
template <typename OutT>
__global__ __launch_bounds__(256)
void gemm_bt(const bf16* __restrict__ A, const bf16* __restrict__ Bt,
             OutT* __restrict__ C, int M, int N, int K, int lda, int ldc)
{
    __shared__ bf16 As[128 * BK];
    __shared__ bf16 Bs[128 * BK];
    int tid = threadIdx.x;
    int lane = tid & 63;
    int wid = tid >> 6;
    int wy = wid >> 1, wx = wid & 1;

    int nwg = gridDim.x * gridDim.y;
    int bid = blockIdx.y * gridDim.x + blockIdx.x;
    int swz = (bid & 7) * (nwg >> 3) + (bid >> 3);   // contiguous chunk per XCD
    int bx = swz % gridDim.x, by = swz / gridDim.x;
    int m0 = by * 128, n0 = bx * 128;

    f4 acc[4][4];
    #pragma unroll
    for (int mi = 0; mi < 4; ++mi)
        #pragma unroll
        for (int ni = 0; ni < 4; ++ni)
            acc[mi][ni] = (f4){0.f, 0.f, 0.f, 0.f};

    int srow = lane >> 2;
    int scol = (lane & 3) * 8;
    for (int kt = 0; kt < K; kt += BK) {
        #pragma unroll
        for (int i = 0; i < 2; ++i) {
            int chunk = wid * 2 + i;
            int row = chunk * 16 + srow;
            stage16(A  + (long)(m0 + row) * lda + kt + scol, As + chunk * 512 + lane * 8);
            stage16(Bt + (long)(n0 + row) * K   + kt + scol, Bs + chunk * 512 + lane * 8);
        }
        __syncthreads();
        bf16x8 af[4], bfr[4];
        #pragma unroll
        for (int mi = 0; mi < 4; ++mi)
            af[mi] = *(const bf16x8*)&As[(wy * 64 + mi * 16 + (lane & 15)) * BK + (lane >> 4) * 8];
        #pragma unroll
        for (int ni = 0; ni < 4; ++ni)
            bfr[ni] = *(const bf16x8*)&Bs[(wx * 64 + ni * 16 + (lane & 15)) * BK + (lane >> 4) * 8];
        #pragma unroll
        for (int mi = 0; mi < 4; ++mi)
            #pragma unroll
            for (int ni = 0; ni < 4; ++ni)
                acc[mi][ni] = __builtin_amdgcn_mfma_f32_16x16x32_bf16(af[mi], bfr[ni], acc[mi][ni], 0, 0, 0);
        __syncthreads();
    }
    #pragma unroll
    for (int mi = 0; mi < 4; ++mi) {
        int rbase = m0 + wy * 64 + mi * 16 + (lane >> 4) * 4;
        #pragma unroll
        for (int ni = 0; ni < 4; ++ni) {
            int col = n0 + wx * 64 + ni * 16 + (lane & 15);
            #pragma unroll
            for (int r = 0; r < 4; ++r)
                C[(long)(rbase + r) * ldc + col] = (OutT)acc[mi][ni][r];
        }
    }
}

// ---------------- GEMM 256x256 8-phase (T3+T4+T5), bf16 out ---------------
// C[M,N] = A[M,K] x Bt[N,K]^T. 512 threads = 8 waves (2M x 4N); per-wave
// 128x64 output (8x4 16x16 frags). BK=64; LDS 128KB: As/Bs each
// [2 dbuf][2 half][128][64]. Counted vmcnt(8) = 4 half-tiles in flight.
#define VM8  asm volatile("s_waitcnt vmcnt(8)" ::: "memory")
#define CLOB asm volatile("" ::: "memory")
#define BARR __builtin_amdgcn_s_barrier()

__global__ __launch_bounds__(512)
void gemm256(const bf16* __restrict__ A, const bf16* __restrict__ Bt,
             bf16* __restrict__ C, int M, int N, int K, int ldc)
{
    extern __shared__ bf16 lds[];            // As = lds[0..32767], Bs = +32768
    bf16* Asl = lds;
    bf16* Bsl = lds + 32768;
    int tid = threadIdx.x;
    int lane = tid & 63, wid = tid >> 6;
    int wm = wid >> 2, wn = wid & 3;
    int quad = lane >> 4, col = lane & 15;

    int nwg = gridDim.x * gridDim.y;
    int bid = blockIdx.y * gridDim.x + blockIdx.x;
    int swz = (bid & 7) * (nwg >> 3) + (bid >> 3);
    int bx = swz % gridDim.x, by = swz / gridDim.x;
    int m0 = by * 256, n0 = bx * 256;

    int NT = K >> 6;                          // 64-wide K tiles
    // staging thread map: per half-tile (128 rows x 64 k), 2 loads/thread
    int srow0 = wid * 8 + (lane >> 3);        // + i*64
    int scol0 = (lane & 7) * 8;

    f4 acc[8][4];
    #pragma unroll
    for (int mi = 0; mi < 8; ++mi)
        #pragma unroll
        for (int ni = 0; ni < 4; ++ni)
            acc[mi][ni] = (f4){0.f, 0.f, 0.f, 0.f};

    // stage stream: s%4: 0->B0(s/4) 1->A0 2->B1 3->A1; clamp tile to NT-1.
    #define STAGE_S(sv) do {                                                   \
        int _s = (sv);                                                         \
        int _ts = _s >> 2; if (_ts > NT - 1) _ts = NT - 1;                     \
        int _c = _s & 3;                                                       \
        const bf16* _mat = (_c & 1) ? A : Bt;                                  \
        int _hh = _c >> 1;                                                     \
        bf16* _base = ((_c & 1) ? Asl : Bsl) + ((_ts & 1) * 2 + _hh) * 8192;   \
        int _rb = ((_c & 1) ? m0 : n0) + _hh * 128;                            \
        _Pragma("unroll")                                                      \
        for (int _i = 0; _i < 2; ++_i)                                         \
            stage16(_mat + (long)(_rb + _i * 64 + srow0) * K + _ts * 64 + scol0,\
                    _base + (_i * 64 + srow0) * 64 + scol0);                   \
    } while (0)

    // prologue: B0(0) A0(0) B1(0) A1(0) B0(1) A0(1)  (s = 0..5)
    #pragma unroll
    for (int s = 0; s < 6; ++s) STAGE_S(s);
    int s = 6;

    bf16x8 a[4][2], bb[2][2][2];
    int aoff0 = (wm * 128 + col) * 64 + quad * 8;             // + b*16384
    int boff0 = ((wn >> 1) * 128 + (wn & 1) * 64 + col) * 64 + quad * 8;

    for (int t = 0; t < NT; ++t) {
        int b = t & 1;
        int aoff = b * 16384 + aoff0;
        int boff = b * 16384 + boff0;
        // ---- p1: quadrant (qm=0, qn=0); stage B1(t+1) ----
        VM8; STAGE_S(s); ++s; CLOB; BARR; CLOB;
        #pragma unroll
        for (int mi = 0; mi < 4; ++mi)
            #pragma unroll
            for (int kk = 0; kk < 2; ++kk)
                a[mi][kk] = *(const bf16x8*)&Asl[aoff + mi * 1024 + kk * 32];
        #pragma unroll
        for (int ni = 0; ni < 2; ++ni)
            #pragma unroll
            for (int kk = 0; kk < 2; ++kk)
                bb[0][ni][kk] = *(const bf16x8*)&Bsl[boff + ni * 1024 + kk * 32];
        __builtin_amdgcn_s_setprio(1);
        #pragma unroll
        for (int mi = 0; mi < 4; ++mi)
            #pragma unroll
            for (int ni = 0; ni < 2; ++ni)
                #pragma unroll
                for (int kk = 0; kk < 2; ++kk)
                    acc[mi][ni] = __builtin_amdgcn_mfma_f32_16x16x32_bf16(a[mi][kk], bb[0][ni][kk], acc[mi][ni], 0, 0, 0);
        __builtin_amdgcn_s_setprio(0);
        CLOB; BARR;
        // ---- p2: quadrant (0,1); stage A1(t+1) ----
        VM8; STAGE_S(s); ++s; CLOB; BARR; CLOB;
        #pragma unroll
        for (int ni = 0; ni < 2; ++ni)
            #pragma unroll
            for (int kk = 0; kk < 2; ++kk)
                bb[1][ni][kk] = *(const bf16x8*)&Bsl[boff + 2048 + ni * 1024 + kk * 32];
        __builtin_amdgcn_s_setprio(1);
        #pragma unroll
        for (int mi = 0; mi < 4; ++mi)
            #pragma unroll
            for (int ni = 0; ni < 2; ++ni)
                #pragma unroll
                for (int kk = 0; kk < 2; ++kk)
                    acc[mi][2 + ni] = __builtin_amdgcn_mfma_f32_16x16x32_bf16(a[mi][kk], bb[1][ni][kk], acc[mi][2 + ni], 0, 0, 0);
        __builtin_amdgcn_s_setprio(0);
        CLOB; BARR;
        // ---- p3: quadrant (1,1); stage B0(t+2) ----
        VM8; STAGE_S(s); ++s; CLOB; BARR; CLOB;
        #pragma unroll
        for (int mi = 0; mi < 4; ++mi)
            #pragma unroll
            for (int kk = 0; kk < 2; ++kk)
                a[mi][kk] = *(const bf16x8*)&Asl[aoff + 4096 + mi * 1024 + kk * 32];
        __builtin_amdgcn_s_setprio(1);
        #pragma unroll
        for (int mi = 0; mi < 4; ++mi)
            #pragma unroll
            for (int ni = 0; ni < 2; ++ni)
                #pragma unroll
                for (int kk = 0; kk < 2; ++kk)
                    acc[4 + mi][2 + ni] = __builtin_amdgcn_mfma_f32_16x16x32_bf16(a[mi][kk], bb[1][ni][kk], acc[4 + mi][2 + ni], 0, 0, 0);
        __builtin_amdgcn_s_setprio(0);
        CLOB; BARR;
        // ---- p4: quadrant (1,0); stage A0(t+2) ----
        STAGE_S(s); ++s; CLOB; BARR; CLOB;
        __builtin_amdgcn_s_setprio(1);
        #pragma unroll
        for (int mi = 0; mi < 4; ++mi)
            #pragma unroll
            for (int ni = 0; ni < 2; ++ni)
                #pragma unroll
                for (int kk = 0; kk < 2; ++kk)
                    acc[4 + mi][ni] = __builtin_amdgcn_mfma_f32_16x16x32_bf16(a[mi][kk], bb[0][ni][kk], acc[4 + mi][ni], 0, 0, 0);
        __builtin_amdgcn_s_setprio(0);
        CLOB; BARR;
    }
    #undef STAGE_S

    #pragma unroll
    for (int mi = 0; mi < 8; ++mi) {
        int rbase = m0 + wm * 128 + mi * 16 + quad * 4;
        #pragma unroll
        for (int ni = 0; ni < 4; ++ni) {
            int cc = n0 + wn * 64 + ni * 16 + col;
            #pragma unroll
            for (int r = 0; r < 4; ++r)
                C[(long)(rbase + r) * ldc + cc] = (bf16)acc[mi][ni][r];
        }
    }
}

// ---------------- MFMA flash attention, v6 (verified R12 structure) -------
#define QS 72
#define C_SL 0.18033688011112042f   // 0.125 * log2(e)

__device__ __forceinline__ int vsw(int d, int k) {
    return d * 64 + ((((k >> 3) ^ (d & 7) ^ ((d >> 3) & 7)) & 7) << 3) + (k & 7);
}

__global__ __launch_bounds__(256)
void attn_mfma(bf16* __restrict__ qkv)
{
    __shared__ bf16 Ks[64 * QS];        //  9.2 KB
    __shared__ bf16 Vt[64 * 64];        //  8.0 KB (swizzled)
    __shared__ bf16 Ps[4 * 32 * QS];    // 18.4 KB
    const int T = 2048, D3 = 3072;
    int tid = threadIdx.x;
    int lane = tid & 63, wid = tid >> 6;
    int quad = lane >> 4, col = lane & 15;
    int bh = blockIdx.x & 63;
    int qt = 15 - (blockIdx.x >> 6);     // heavy tiles dispatched first
    int b = bh >> 4, h = bh & 15;
    long base = (long)b * T * D3 + h * 64;
    int q0 = qt * 128;
    int nk = 2 * qt + 2;
    int srow = tid >> 2, dseg = (tid & 3) * 16;   // 64x64 staging map
    bf16* Pw = &Ps[wid * 32 * QS];

    // Q B-frags (held in regs): lane holds Q[q=nt*16+col][d=quad*8+j+32*ch]
    bf16x8 aq[2][2];
    #pragma unroll
    for (int nt = 0; nt < 2; ++nt) {
        const bf16* gq = &qkv[base + (long)(q0 + wid * 32 + nt * 16 + col) * D3 + quad * 8];
        aq[nt][0] = *(const bf16x8*)gq;
        aq[nt][1] = *(const bf16x8*)(gq + 32);
    }
    bf16 one1 = (bf16)1.0f;
    bf16x8 bones = {one1, one1, one1, one1, one1, one1, one1, one1};

    f4 of[2][4], lac[2];
    #pragma unroll
    for (int mg = 0; mg < 2; ++mg) {
        lac[mg] = (f4){0.f, 0.f, 0.f, 0.f};
        #pragma unroll
        for (int n = 0; n < 4; ++n) of[mg][n] = (f4){0.f, 0.f, 0.f, 0.f};
    }

    // prefetch k-tile 0
    const bf16* g0 = &qkv[base + (long)srow * D3 + 1024 + dseg];
    bf16x8 kr0 = *(const bf16x8*)g0;
    bf16x8 kr1 = *(const bf16x8*)(g0 + 8);
    bf16x8 vr0 = *(const bf16x8*)(g0 + 1024);
    bf16x8 vr1 = *(const bf16x8*)(g0 + 1032);

    for (int kt = 0; kt < nk; ++kt) {
        __syncthreads();                 // prior iter's LDS reads done
        *(bf16x8*)&Ks[srow * QS + dseg]     = kr0;
        *(bf16x8*)&Ks[srow * QS + dseg + 8] = kr1;
        #pragma unroll
        for (int j = 0; j < 8; ++j) {
            Vt[vsw(dseg + j, srow)]     = vr0[j];
            Vt[vsw(dseg + 8 + j, srow)] = vr1[j];
        }
        if (kt + 1 < nk) {               // latency hidden behind compute
            const bf16* gn = &qkv[base + (long)((kt + 1) * 64 + srow) * D3 + 1024 + dseg];
            kr0 = *(const bf16x8*)gn;
            kr1 = *(const bf16x8*)(gn + 8);
            vr0 = *(const bf16x8*)(gn + 1024);
            vr1 = *(const bf16x8*)(gn + 1032);
        }
        __syncthreads();
        // S^T = K Q^T, fused per 16-row k-chunk (bounds live registers)
        bool diag = (kt >= nk - 2);
        int k0 = kt * 64;
        #pragma unroll
        for (int mt = 0; mt < 4; ++mt) {
            bf16x8 ak0 = *(const bf16x8*)&Ks[(mt * 16 + col) * QS + quad * 8];
            bf16x8 ak1 = *(const bf16x8*)&Ks[(mt * 16 + col) * QS + 32 + quad * 8];
            #pragma unroll
            for (int nt = 0; nt < 2; ++nt) {
                f4 z = (f4){0.f, 0.f, 0.f, 0.f};
                __builtin_amdgcn_s_setprio(1);
                z = __builtin_amdgcn_mfma_f32_16x16x32_bf16(ak0, aq[nt][0], z, 0, 0, 0);
                f4 st = __builtin_amdgcn_mfma_f32_16x16x32_bf16(ak1, aq[nt][1], z, 0, 0, 0);
                __builtin_amdgcn_s_setprio(0);
                bf16x4 pk;
                if (diag) {
                    int qg = q0 + wid * 32 + nt * 16 + col;
                    #pragma unroll
                    for (int r = 0; r < 4; ++r) {
                        float arg = fmaf(st[r], C_SL, -16.f);
                        if ((k0 + mt * 16 + quad * 4 + r) > qg) arg = -1e30f;
                        pk[r] = (bf16)exp2f(arg);
                    }
                } else {
                    #pragma unroll
                    for (int r = 0; r < 4; ++r)
                        pk[r] = (bf16)exp2f(fmaf(st[r], C_SL, -16.f));
                }
                *(bf16x4*)&Pw[(nt * 16 + col) * QS + mt * 16 + quad * 4] = pk;
            }
        }
        // P readback (wave-private, no barrier): hoisted A-frags
        bf16x8 ap[2][2];
        #pragma unroll
        for (int mg = 0; mg < 2; ++mg) {
            ap[mg][0] = *(const bf16x8*)&Pw[(mg * 16 + col) * QS + quad * 8];
            ap[mg][1] = *(const bf16x8*)&Pw[(mg * 16 + col) * QS + 32 + quad * 8];
        }
        // O += P V: nd-major so each V frag pair is read ONCE (8 b128/iter)
        #pragma unroll
        for (int nd = 0; nd < 4; ++nd) {
            bf16x8 bv0 = *(const bf16x8*)&Vt[vsw(nd * 16 + col, quad * 8)];
            bf16x8 bv1 = *(const bf16x8*)&Vt[vsw(nd * 16 + col, 32 + quad * 8)];
            __builtin_amdgcn_s_setprio(1);
            of[0][nd] = __builtin_amdgcn_mfma_f32_16x16x32_bf16(ap[0][0], bv0, of[0][nd], 0, 0, 0);
            of[0][nd] = __builtin_amdgcn_mfma_f32_16x16x32_bf16(ap[0][1], bv1, of[0][nd], 0, 0, 0);
            of[1][nd] = __builtin_amdgcn_mfma_f32_16x16x32_bf16(ap[1][0], bv0, of[1][nd], 0, 0, 0);
            of[1][nd] = __builtin_amdgcn_mfma_f32_16x16x32_bf16(ap[1][1], bv1, of[1][nd], 0, 0, 0);
            __builtin_amdgcn_s_setprio(0);
        }
        // l += P 1
        __builtin_amdgcn_s_setprio(1);
        #pragma unroll
        for (int mg = 0; mg < 2; ++mg) {
            lac[mg] = __builtin_amdgcn_mfma_f32_16x16x32_bf16(ap[mg][0], bones, lac[mg], 0, 0, 0);
            lac[mg] = __builtin_amdgcn_mfma_f32_16x16x32_bf16(ap[mg][1], bones, lac[mg], 0, 0, 0);
        }
        __builtin_amdgcn_s_setprio(0);
    }
    // epilogue: y into this block's dead Q region; l is in O's C-layout
    #pragma unroll
    for (int mg = 0; mg < 2; ++mg)
        #pragma unroll
        for (int r = 0; r < 4; ++r) {
            float inv = 1.f / lac[mg][r];
            long yoff = base + (long)(q0 + wid * 32 + mg * 16 + quad * 4 + r) * D3;
            #pragma unroll
            for (int nd = 0; nd < 4; ++nd)
                qkv[yoff + nd * 16 + col] = (bf16)(of[mg][nd][r] * inv);
        }
}

// --------------------------------------------------------------------------
extern "C" void kernel_launch(void* const* d_in, const int* in_sizes, int n_in,
                              void* d_out, int out_size, void* d_ws, size_t ws_size,
                              hipStream_t stream) {
    const float* x      = (const float*)d_in[0];  // [8192,1024] fp32
    const float* W_attn = (const float*)d_in[1];  // [1024,3072] fp32
    const float* W_proj = (const float*)d_in[2];  // [1024,1024] fp32
    float* out = (float*)d_out;                   // [8192,1024] fp32

    // ws layout (58.7 MB): qkv | WtA | WtP
    bf16* qkv = (bf16*)d_ws;                         // [8192,3072]  50.3 MB
    bf16* WtA = qkv + (size_t)8192 * 3072;           // [3072,1024]   6.3 MB
    bf16* WtP = WtA + (size_t)3072 * 1024;           // [1024,1024]   2.1 MB
    bf16* xb = (bf16*)d_out;   // bf16 x staged in d_out; dead before gemm2

    static bool attr_set = false;
    if (!attr_set) {
        hipFuncSetAttribute((const void*)gemm256,
                            hipFuncAttributeMaxDynamicSharedMemorySize, 131072);
        attr_set = true;
    }

    cast_f32_bf16<<<8192, 256, 0, stream>>>(x, xb, 8192 * 1024 / 4);
    transpose_f32_bf16<<<dim3(48, 16), 256, 0, stream>>>(W_attn, WtA, 1024, 3072);
    transpose_f32_bf16<<<dim3(16, 16), 256, 0, stream>>>(W_proj, WtP, 1024, 1024);
    // qkv = xb @ W_attn  (bf16 out): 256^2 8-phase kernel, grid 12x32
    gemm256<<<dim3(12, 32), 512, 131072, stream>>>(xb, WtA, qkv, 8192, 3072,
                                                   1024, 3072);
    // MFMA flash attention; y written into qkv's Q columns
    attn_mfma<<<1024, 256, 0, stream>>>(qkv);
    // out = y @ W_proj  (y = qkv cols 0..1023, row stride 3072; fp32 out)
    gemm_bt<float><<<dim3(8, 64), 256, 0, stream>>>(qkv, WtP, out, 8192, 1024,
                                                    1024, 3072, 1024);
}

// Round 6
// 265.236 us; speedup vs baseline: 1.0667x; 1.0667x over previous
//
#include <hip/hip_runtime.h>

// B=4, T=2048, D=1024, H=16, hd=64. Inputs/output fp32; internal bf16 MFMA.
// R16: fix gemm256's three defects found in R15 counters (556 TF, 14.2M
// bank conflicts, MfmaUtil 22%):
//  1) T2 swizzle: staging pre-swizzles the GLOBAL source col
//     (swcol = ((lane&7)^(lane>>3&7))*8, LDS dest stays linear per
//     gload_lds constraint); reads XOR k-slot bytes with (col&7)<<4.
//     16-way -> conflict-free b128 reads.
//  2) phase shape: ds_reads issued BEFORE the phase barrier (latency hides
//     under other waves' MFMAs), MFMA after barrier, 2 barriers/phase.
//  3) correct waits: stage B(t+2)@p3 (B-reads done at p2-end barrier),
//     stage A(t+2)+vmcnt(8)@p4 (A-reads done at p3-end); vmcnt precedes
//     p4's barrier so ALL waves' staging is landed before p1(t+1) reads.
//     Tail drains with vmcnt(0). One vmcnt per K-tile, never mid-phase.
// attn = verified R12 structure; gemm2 = verified 128^2 path (controls).

typedef __bf16 bf16;
typedef __attribute__((ext_vector_type(8))) __bf16 bf16x8;
typedef __attribute__((ext_vector_type(4))) __bf16 bf16x4;
typedef __attribute__((ext_vector_type(4))) float f4;

#define BK 32

__device__ __forceinline__ void stage16(const bf16* g, bf16* l) {
    __builtin_amdgcn_global_load_lds((const __attribute__((address_space(1))) void*)g,
                                     (__attribute__((address_space(3))) void*)l,
                                     16, 0, 0);
}

// ---------------- cast fp32 -> bf16, vectorized ---------------------------
__global__ __launch_bounds__(256)
void cast_f32_bf16(const float* __restrict__ src, bf16* __restrict__ dst, int n4)
{
    int i = blockIdx.x * 256 + threadIdx.x;
    if (i < n4) {
        float4 v = ((const float4*)src)[i];
        bf16x4 o = { (bf16)v.x, (bf16)v.y, (bf16)v.z, (bf16)v.w };
        *(bf16x4*)&dst[i * 4] = o;
    }
}

// ---------------- transpose + cast: fp32 src [R][C] -> bf16 dst [C][R] ----
__global__ __launch_bounds__(256)
void transpose_f32_bf16(const float* __restrict__ src, bf16* __restrict__ dst,
                        int R, int C)
{
    __shared__ bf16 tile[64][65];
    int c0 = blockIdx.x * 64, r0 = blockIdx.y * 64;
    int tid = threadIdx.x;
    for (int i = tid; i < 64 * 64; i += 256) {
        int r = i >> 6, c = i & 63;
        tile[r][c] = (bf16)src[(long)(r0 + r) * C + c0 + c];
    }
    __syncthreads();
    for (int i = tid; i < 64 * 64; i += 256) {
        int r = i >> 6, c = i & 63;
        dst[(long)(c0 + r) * R + r0 + c] = tile[c][r];
    }
}

// ---------------- GEMM: C[M,N] = A[M,K] x Bt[N,K]^T, bf16 in, OutT out ----
// 128x128 tile, BK=32, global_load_lds width-16 staging (m97 pattern).
// + T1 XCD-aware block swizzle (requires nwg % 8 == 0; holds: 512).
template <typename OutT>
__global__ __launch_bounds__(256)
void gemm_bt(const bf16* __restrict__ A, const bf16* __restrict__ Bt,
             OutT* __restrict__ C, int M, int N, int K, int lda, int ldc)
{
    __shared__ bf16 As[128 * BK];
    __shared__ bf16 Bs[128 * BK];
    int tid = threadIdx.x;
    int lane = tid & 63;
    int wid = tid >> 6;
    int wy = wid >> 1, wx = wid & 1;

    int nwg = gridDim.x * gridDim.y;
    int bid = blockIdx.y * gridDim.x + blockIdx.x;
    int swz = (bid & 7) * (nwg >> 3) + (bid >> 3);   // contiguous chunk per XCD
    int bx = swz % gridDim.x, by = swz / gridDim.x;
    int m0 = by * 128, n0 = bx * 128;

    f4 acc[4][4];
    #pragma unroll
    for (int mi = 0; mi < 4; ++mi)
        #pragma unroll
        for (int ni = 0; ni < 4; ++ni)
            acc[mi][ni] = (f4){0.f, 0.f, 0.f, 0.f};

    int srow = lane >> 2;
    int scol = (lane & 3) * 8;
    for (int kt = 0; kt < K; kt += BK) {
        #pragma unroll
        for (int i = 0; i < 2; ++i) {
            int chunk = wid * 2 + i;
            int row = chunk * 16 + srow;
            stage16(A  + (long)(m0 + row) * lda + kt + scol, As + chunk * 512 + lane * 8);
            stage16(Bt + (long)(n0 + row) * K   + kt + scol, Bs + chunk * 512 + lane * 8);
        }
        __syncthreads();
        bf16x8 af[4], bfr[4];
        #pragma unroll
        for (int mi = 0; mi < 4; ++mi)
            af[mi] = *(const bf16x8*)&As[(wy * 64 + mi * 16 + (lane & 15)) * BK + (lane >> 4) * 8];
        #pragma unroll
        for (int ni = 0; ni < 4; ++ni)
            bfr[ni] = *(const bf16x8*)&Bs[(wx * 64 + ni * 16 + (lane & 15)) * BK + (lane >> 4) * 8];
        #pragma unroll
        for (int mi = 0; mi < 4; ++mi)
            #pragma unroll
            for (int ni = 0; ni < 4; ++ni)
                acc[mi][ni] = __builtin_amdgcn_mfma_f32_16x16x32_bf16(af[mi], bfr[ni], acc[mi][ni], 0, 0, 0);
        __syncthreads();
    }
    #pragma unroll
    for (int mi = 0; mi < 4; ++mi) {
        int rbase = m0 + wy * 64 + mi * 16 + (lane >> 4) * 4;
        #pragma unroll
        for (int ni = 0; ni < 4; ++ni) {
            int col = n0 + wx * 64 + ni * 16 + (lane & 15);
            #pragma unroll
            for (int r = 0; r < 4; ++r)
                C[(long)(rbase + r) * ldc + col] = (OutT)acc[mi][ni][r];
        }
    }
}

// ---------------- GEMM 256x256 8-phase (T2+T3+T4+T5), bf16 out ------------
// C[M,N] = A[M,K] x Bt[N,K]^T. 512 thr = 8 waves (2M x 4N); per-wave 128x64
// out. BK=64; LDS 128KB = 2 dbuf x [A 256x64 | B 256x64], st-16x32 swizzled.
#define VMW8 asm volatile("s_waitcnt vmcnt(8)" ::: "memory")
#define VMW0 asm volatile("s_waitcnt vmcnt(0)" ::: "memory")
#define CLOB asm volatile("" ::: "memory")
#define BARR __builtin_amdgcn_s_barrier()
#define SB0  __builtin_amdgcn_sched_barrier(0)

__global__ __launch_bounds__(512)
void gemm256(const bf16* __restrict__ A, const bf16* __restrict__ Bt,
             bf16* __restrict__ C, int M, int N, int K, int ldc)
{
    extern __shared__ bf16 lds[];
    bf16* Asl = lds;                  // [2][256][64]
    bf16* Bsl = lds + 32768;          // [2][256][64]
    int tid = threadIdx.x;
    int lane = tid & 63, wid = tid >> 6;
    int wm = wid >> 2, wn = wid & 3;
    int quad = lane >> 4, col = lane & 15;

    int nwg = gridDim.x * gridDim.y;
    int bid = blockIdx.y * gridDim.x + blockIdx.x;
    int swz = (bid & 7) * (nwg >> 3) + (bid >> 3);
    int bx = swz % gridDim.x, by = swz / gridDim.x;
    int m0 = by * 256, n0 = bx * 256;

    int NT = K >> 6;
    // staging map: row = wid*8 + lane>>3 (+64*_i, +128*half); LINEAR dest col,
    // swizzled (involution) SOURCE col so phys slot s holds logical s^(row&7).
    int srow = wid * 8 + (lane >> 3);
    int lincol = (lane & 7) * 8;
    int swcol  = ((lane & 7) ^ ((lane >> 3) & 7)) * 8;
    // read-side: k-slot byte offset XOR (row&7)<<4; row&7 == col&7 everywhere.
    int xorv = (col & 7) << 4;
    int ke0 = ((quad * 16) ^ xorv) >> 1;
    int ke1 = ((quad * 16 + 64) ^ xorv) >> 1;

    f4 acc[8][4];
    #pragma unroll
    for (int mi = 0; mi < 8; ++mi)
        #pragma unroll
        for (int ni = 0; ni < 4; ++ni)
            acc[mi][ni] = (f4){0.f, 0.f, 0.f, 0.f};

    #define STG_HALF(mat, rb, ts, dstb) do {                                    \
        _Pragma("unroll")                                                       \
        for (int _i = 0; _i < 2; ++_i)                                          \
            stage16((mat) + (long)((rb) + _i * 64 + srow) * K + (ts) * 64 + swcol, \
                    (dstb) + (_i * 64 + srow) * 64 + lincol);                   \
    } while (0)
    #define STGB(ts) do { bf16* _d = Bsl + ((ts) & 1) * 16384;                  \
        STG_HALF(Bt, n0,       (ts), _d);                                       \
        STG_HALF(Bt, n0 + 128, (ts), _d + 8192); } while (0)
    #define STGA(ts) do { bf16* _d = Asl + ((ts) & 1) * 16384;                  \
        STG_HALF(A,  m0,       (ts), _d);                                       \
        STG_HALF(A,  m0 + 128, (ts), _d + 8192); } while (0)

    bf16x8 a[4][2], bb[2][2][2];
    #define RD_A(qm) do { _Pragma("unroll")                                     \
        for (int mi = 0; mi < 4; ++mi) {                                        \
            int _r = ab + ((qm) * 64 + mi * 16) * 64;                           \
            a[mi][0] = *(const bf16x8*)&Asl[_r + ke0];                          \
            a[mi][1] = *(const bf16x8*)&Asl[_r + ke1]; } } while (0)
    #define RD_B(qn) do { _Pragma("unroll")                                     \
        for (int ni = 0; ni < 2; ++ni) {                                        \
            int _r = bbo + ((qn) * 32 + ni * 16) * 64;                          \
            bb[qn][ni][0] = *(const bf16x8*)&Bsl[_r + ke0];                     \
            bb[qn][ni][1] = *(const bf16x8*)&Bsl[_r + ke1]; } } while (0)
    #define MM(qm, qn) do { __builtin_amdgcn_s_setprio(1);                      \
        _Pragma("unroll")                                                       \
        for (int mi = 0; mi < 4; ++mi)                                          \
            _Pragma("unroll")                                                   \
            for (int ni = 0; ni < 2; ++ni)                                      \
                _Pragma("unroll")                                               \
                for (int kk = 0; kk < 2; ++kk)                                  \
                    acc[(qm)*4+mi][(qn)*2+ni] =                                 \
                        __builtin_amdgcn_mfma_f32_16x16x32_bf16(                \
                            a[mi][kk], bb[qn][ni][kk],                          \
                            acc[(qm)*4+mi][(qn)*2+ni], 0, 0, 0);                \
        __builtin_amdgcn_s_setprio(0); } while (0)

    // prologue: tiles 0 and 1 staged; oldest 8 ops (tile 0) landed, barrier.
    STGB(0); STGA(0); STGB(1); STGA(1);
    VMW8; CLOB; BARR; CLOB;

    for (int t = 0; t < NT; ++t) {
        int b = t & 1;
        int ab  = b * 16384 + (wm * 128 + col) * 64;
        int bbo = b * 16384 + (wn * 64 + col) * 64;
        // p1: reads for quad(0,0); barrier; MFMA
        RD_A(0); RD_B(0);
        CLOB; BARR; SB0; MM(0, 0); CLOB; BARR;
        // p2: reads b-high; quad(0,1).  (all B reads complete by end-barrier)
        RD_B(1);
        CLOB; BARR; SB0; MM(0, 1); CLOB; BARR;
        // p3: reads a-high; stage B(t+2) (B region free); quad(1,1)
        RD_A(1);
        if (t + 2 < NT) STGB(t + 2);
        CLOB; BARR; SB0; MM(1, 1); CLOB; BARR;
        // p4: stage A(t+2) (A region free); vmcnt guarantees tile t+1 landed
        // across ALL waves once past the barrier; quad(1,0) reuses regs.
        if (t + 2 < NT) { STGA(t + 2); VMW8; }
        else if (t + 1 < NT) { VMW0; }
        CLOB; BARR; SB0; MM(1, 0); CLOB; BARR;
    }
    #undef STG_HALF
    #undef STGB
    #undef STGA
    #undef RD_A
    #undef RD_B
    #undef MM

    #pragma unroll
    for (int mi = 0; mi < 8; ++mi) {
        int rbase = m0 + wm * 128 + mi * 16 + quad * 4;
        #pragma unroll
        for (int ni = 0; ni < 4; ++ni) {
            int cc = n0 + wn * 64 + ni * 16 + col;
            #pragma unroll
            for (int r = 0; r < 4; ++r)
                C[(long)(rbase + r) * ldc + cc] = (bf16)acc[mi][ni][r];
        }
    }
}

// ---------------- MFMA flash attention, v6 (verified R12 structure) -------
#define QS 72
#define C_SL 0.18033688011112042f   // 0.125 * log2(e)

__device__ __forceinline__ int vsw(int d, int k) {
    return d * 64 + ((((k >> 3) ^ (d & 7) ^ ((d >> 3) & 7)) & 7) << 3) + (k & 7);
}

__global__ __launch_bounds__(256)
void attn_mfma(bf16* __restrict__ qkv)
{
    __shared__ bf16 Ks[64 * QS];        //  9.2 KB
    __shared__ bf16 Vt[64 * 64];        //  8.0 KB (swizzled)
    __shared__ bf16 Ps[4 * 32 * QS];    // 18.4 KB
    const int T = 2048, D3 = 3072;
    int tid = threadIdx.x;
    int lane = tid & 63, wid = tid >> 6;
    int quad = lane >> 4, col = lane & 15;
    int bh = blockIdx.x & 63;
    int qt = 15 - (blockIdx.x >> 6);     // heavy tiles dispatched first
    int b = bh >> 4, h = bh & 15;
    long base = (long)b * T * D3 + h * 64;
    int q0 = qt * 128;
    int nk = 2 * qt + 2;
    int srow = tid >> 2, dseg = (tid & 3) * 16;   // 64x64 staging map
    bf16* Pw = &Ps[wid * 32 * QS];

    // Q B-frags (held in regs): lane holds Q[q=nt*16+col][d=quad*8+j+32*ch]
    bf16x8 aq[2][2];
    #pragma unroll
    for (int nt = 0; nt < 2; ++nt) {
        const bf16* gq = &qkv[base + (long)(q0 + wid * 32 + nt * 16 + col) * D3 + quad * 8];
        aq[nt][0] = *(const bf16x8*)gq;
        aq[nt][1] = *(const bf16x8*)(gq + 32);
    }
    bf16 one1 = (bf16)1.0f;
    bf16x8 bones = {one1, one1, one1, one1, one1, one1, one1, one1};

    f4 of[2][4], lac[2];
    #pragma unroll
    for (int mg = 0; mg < 2; ++mg) {
        lac[mg] = (f4){0.f, 0.f, 0.f, 0.f};
        #pragma unroll
        for (int n = 0; n < 4; ++n) of[mg][n] = (f4){0.f, 0.f, 0.f, 0.f};
    }

    // prefetch k-tile 0
    const bf16* g0 = &qkv[base + (long)srow * D3 + 1024 + dseg];
    bf16x8 kr0 = *(const bf16x8*)g0;
    bf16x8 kr1 = *(const bf16x8*)(g0 + 8);
    bf16x8 vr0 = *(const bf16x8*)(g0 + 1024);
    bf16x8 vr1 = *(const bf16x8*)(g0 + 1032);

    for (int kt = 0; kt < nk; ++kt) {
        __syncthreads();                 // prior iter's LDS reads done
        *(bf16x8*)&Ks[srow * QS + dseg]     = kr0;
        *(bf16x8*)&Ks[srow * QS + dseg + 8] = kr1;
        #pragma unroll
        for (int j = 0; j < 8; ++j) {
            Vt[vsw(dseg + j, srow)]     = vr0[j];
            Vt[vsw(dseg + 8 + j, srow)] = vr1[j];
        }
        if (kt + 1 < nk) {               // latency hidden behind compute
            const bf16* gn = &qkv[base + (long)((kt + 1) * 64 + srow) * D3 + 1024 + dseg];
            kr0 = *(const bf16x8*)gn;
            kr1 = *(const bf16x8*)(gn + 8);
            vr0 = *(const bf16x8*)(gn + 1024);
            vr1 = *(const bf16x8*)(gn + 1032);
        }
        __syncthreads();
        // S^T = K Q^T, fused per 16-row k-chunk (bounds live registers)
        bool diag = (kt >= nk - 2);
        int k0 = kt * 64;
        #pragma unroll
        for (int mt = 0; mt < 4; ++mt) {
            bf16x8 ak0 = *(const bf16x8*)&Ks[(mt * 16 + col) * QS + quad * 8];
            bf16x8 ak1 = *(const bf16x8*)&Ks[(mt * 16 + col) * QS + 32 + quad * 8];
            #pragma unroll
            for (int nt = 0; nt < 2; ++nt) {
                f4 z = (f4){0.f, 0.f, 0.f, 0.f};
                __builtin_amdgcn_s_setprio(1);
                z = __builtin_amdgcn_mfma_f32_16x16x32_bf16(ak0, aq[nt][0], z, 0, 0, 0);
                f4 st = __builtin_amdgcn_mfma_f32_16x16x32_bf16(ak1, aq[nt][1], z, 0, 0, 0);
                __builtin_amdgcn_s_setprio(0);
                bf16x4 pk;
                if (diag) {
                    int qg = q0 + wid * 32 + nt * 16 + col;
                    #pragma unroll
                    for (int r = 0; r < 4; ++r) {
                        float arg = fmaf(st[r], C_SL, -16.f);
                        if ((k0 + mt * 16 + quad * 4 + r) > qg) arg = -1e30f;
                        pk[r] = (bf16)exp2f(arg);
                    }
                } else {
                    #pragma unroll
                    for (int r = 0; r < 4; ++r)
                        pk[r] = (bf16)exp2f(fmaf(st[r], C_SL, -16.f));
                }
                *(bf16x4*)&Pw[(nt * 16 + col) * QS + mt * 16 + quad * 4] = pk;
            }
        }
        // P readback (wave-private, no barrier): hoisted A-frags
        bf16x8 ap[2][2];
        #pragma unroll
        for (int mg = 0; mg < 2; ++mg) {
            ap[mg][0] = *(const bf16x8*)&Pw[(mg * 16 + col) * QS + quad * 8];
            ap[mg][1] = *(const bf16x8*)&Pw[(mg * 16 + col) * QS + 32 + quad * 8];
        }
        // O += P V: nd-major so each V frag pair is read ONCE (8 b128/iter)
        #pragma unroll
        for (int nd = 0; nd < 4; ++nd) {
            bf16x8 bv0 = *(const bf16x8*)&Vt[vsw(nd * 16 + col, quad * 8)];
            bf16x8 bv1 = *(const bf16x8*)&Vt[vsw(nd * 16 + col, 32 + quad * 8)];
            __builtin_amdgcn_s_setprio(1);
            of[0][nd] = __builtin_amdgcn_mfma_f32_16x16x32_bf16(ap[0][0], bv0, of[0][nd], 0, 0, 0);
            of[0][nd] = __builtin_amdgcn_mfma_f32_16x16x32_bf16(ap[0][1], bv1, of[0][nd], 0, 0, 0);
            of[1][nd] = __builtin_amdgcn_mfma_f32_16x16x32_bf16(ap[1][0], bv0, of[1][nd], 0, 0, 0);
            of[1][nd] = __builtin_amdgcn_mfma_f32_16x16x32_bf16(ap[1][1], bv1, of[1][nd], 0, 0, 0);
            __builtin_amdgcn_s_setprio(0);
        }
        // l += P 1
        __builtin_amdgcn_s_setprio(1);
        #pragma unroll
        for (int mg = 0; mg < 2; ++mg) {
            lac[mg] = __builtin_amdgcn_mfma_f32_16x16x32_bf16(ap[mg][0], bones, lac[mg], 0, 0, 0);
            lac[mg] = __builtin_amdgcn_mfma_f32_16x16x32_bf16(ap[mg][1], bones, lac[mg], 0, 0, 0);
        }
        __builtin_amdgcn_s_setprio(0);
    }
    // epilogue: y into this block's dead Q region; l is in O's C-layout
    #pragma unroll
    for (int mg = 0; mg < 2; ++mg)
        #pragma unroll
        for (int r = 0; r < 4; ++r) {
            float inv = 1.f / lac[mg][r];
            long yoff = base + (long)(q0 + wid * 32 + mg * 16 + quad * 4 + r) * D3;
            #pragma unroll
            for (int nd = 0; nd < 4; ++nd)
                qkv[yoff + nd * 16 + col] = (bf16)(of[mg][nd][r] * inv);
        }
}

// --------------------------------------------------------------------------
extern "C" void kernel_launch(void* const* d_in, const int* in_sizes, int n_in,
                              void* d_out, int out_size, void* d_ws, size_t ws_size,
                              hipStream_t stream) {
    const float* x      = (const float*)d_in[0];  // [8192,1024] fp32
    const float* W_attn = (const float*)d_in[1];  // [1024,3072] fp32
    const float* W_proj = (const float*)d_in[2];  // [1024,1024] fp32
    float* out = (float*)d_out;                   // [8192,1024] fp32

    // ws layout (58.7 MB): qkv | WtA | WtP
    bf16* qkv = (bf16*)d_ws;                         // [8192,3072]  50.3 MB
    bf16* WtA = qkv + (size_t)8192 * 3072;           // [3072,1024]   6.3 MB
    bf16* WtP = WtA + (size_t)3072 * 1024;           // [1024,1024]   2.1 MB
    bf16* xb = (bf16*)d_out;   // bf16 x staged in d_out; dead before gemm2

    static bool attr_set = false;
    if (!attr_set) {
        hipFuncSetAttribute((const void*)gemm256,
                            hipFuncAttributeMaxDynamicSharedMemorySize, 131072);
        attr_set = true;
    }

    cast_f32_bf16<<<8192, 256, 0, stream>>>(x, xb, 8192 * 1024 / 4);
    transpose_f32_bf16<<<dim3(48, 16), 256, 0, stream>>>(W_attn, WtA, 1024, 3072);
    transpose_f32_bf16<<<dim3(16, 16), 256, 0, stream>>>(W_proj, WtP, 1024, 1024);
    // qkv = xb @ W_attn  (bf16 out): 256^2 8-phase kernel, grid 12x32
    gemm256<<<dim3(12, 32), 512, 131072, stream>>>(xb, WtA, qkv, 8192, 3072,
                                                   1024, 3072);
    // MFMA flash attention; y written into qkv's Q columns
    attn_mfma<<<1024, 256, 0, stream>>>(qkv);
    // out = y @ W_proj  (y = qkv cols 0..1023, row stride 3072; fp32 out)
    gemm_bt<float><<<dim3(8, 64), 256, 0, stream>>>(qkv, WtP, out, 8192, 1024,
                                                    1024, 3072, 1024);
}

// Round 7
// 255.583 us; speedup vs baseline: 1.1070x; 1.0378x over previous
//
#include <hip/hip_runtime.h>

// B=4, T=2048, D=1024, H=16, hd=64. Inputs/output fp32; internal bf16 MFMA.
// R17: R16's gemm256 reached ~75us (~690 TF) — limited by grid tail: 384
// blocks @ 1 blk/CU = 2 rounds for 1.5 rounds of work (75% ceiling).
// Retile to 128x256 -> 768 blocks = 3*256 EXACTLY (zero tail), LDS 96KB.
// Same verified swizzle + 4-phase counted-vmcnt schedule, resized:
// 6 loads/thr/tile -> vmcnt(6); p1{rdA01+rdB01,MM00} p2{rdB23,MM01}
// p3{rdA23,stgB(t+2),MM11} p4{stgA(t+2),vmcnt6,MM10}. B reads done at
// p2-end, A reads at p3-end -> staging WAR-safe (same proof as R16).
// gemm2 moves to the same kernel: grid 4x64 = 256 blocks = 1 full wave.
// attn = verified R12 structure (80us control).

typedef __bf16 bf16;
typedef __attribute__((ext_vector_type(8))) __bf16 bf16x8;
typedef __attribute__((ext_vector_type(4))) __bf16 bf16x4;
typedef __attribute__((ext_vector_type(4))) float f4;

__device__ __forceinline__ void stage16(const bf16* g, bf16* l) {
    __builtin_amdgcn_global_load_lds((const __attribute__((address_space(1))) void*)g,
                                     (__attribute__((address_space(3))) void*)l,
                                     16, 0, 0);
}

// ---------------- cast fp32 -> bf16, vectorized ---------------------------
__global__ __launch_bounds__(256)
void cast_f32_bf16(const float* __restrict__ src, bf16* __restrict__ dst, int n4)
{
    int i = blockIdx.x * 256 + threadIdx.x;
    if (i < n4) {
        float4 v = ((const float4*)src)[i];
        bf16x4 o = { (bf16)v.x, (bf16)v.y, (bf16)v.z, (bf16)v.w };
        *(bf16x4*)&dst[i * 4] = o;
    }
}

// ---------------- transpose + cast: fp32 src [R][C] -> bf16 dst [C][R] ----
__global__ __launch_bounds__(256)
void transpose_f32_bf16(const float* __restrict__ src, bf16* __restrict__ dst,
                        int R, int C)
{
    __shared__ bf16 tile[64][65];
    int c0 = blockIdx.x * 64, r0 = blockIdx.y * 64;
    int tid = threadIdx.x;
    for (int i = tid; i < 64 * 64; i += 256) {
        int r = i >> 6, c = i & 63;
        tile[r][c] = (bf16)src[(long)(r0 + r) * C + c0 + c];
    }
    __syncthreads();
    for (int i = tid; i < 64 * 64; i += 256) {
        int r = i >> 6, c = i & 63;
        dst[(long)(c0 + r) * R + r0 + c] = tile[c][r];
    }
}

// ---------------- GEMM 128x256 4-phase (T1+T2+T3+T4+T5) -------------------
// C[M,N] = A[M,K] x Bt[N,K]^T; row strides lda/ldb explicit (A may be a
// column-slice of qkv). 512 thr = 8 waves (2M x 4N); per-wave 64x64 out.
// BK=64; LDS 96KB: Asl[2][128][64], Bsl[2][256][64]; st-granule swizzle via
// pre-swizzled global source col (LDS dest linear, rule #21), reads XOR
// k-slot bytes with (col&7)<<4.
#define VMW6 asm volatile("s_waitcnt vmcnt(6)" ::: "memory")
#define VMW0 asm volatile("s_waitcnt vmcnt(0)" ::: "memory")
#define CLOB asm volatile("" ::: "memory")
#define BARR __builtin_amdgcn_s_barrier()
#define SB0  __builtin_amdgcn_sched_barrier(0)

template <typename OutT>
__global__ __launch_bounds__(512)
void gemm256(const bf16* __restrict__ A, const bf16* __restrict__ Bt,
             OutT* __restrict__ C, int lda, int ldb, int ldc, int K)
{
    extern __shared__ bf16 lds[];
    bf16* Asl = lds;                  // [2][128][64]
    bf16* Bsl = lds + 16384;          // [2][256][64]
    int tid = threadIdx.x;
    int lane = tid & 63, wid = tid >> 6;
    int wm = wid >> 2, wn = wid & 3;
    int quad = lane >> 4, col = lane & 15;

    int nwg = gridDim.x * gridDim.y;
    int bid = blockIdx.y * gridDim.x + blockIdx.x;
    int swz = (bid & 7) * (nwg >> 3) + (bid >> 3);
    int bx = swz % gridDim.x, by = swz / gridDim.x;
    int m0 = by * 128, n0 = bx * 256;

    int NT = K >> 6;
    // staging: row = wid*8 + (lane>>3) (+64*_i, +128*half); linear dest col,
    // involution-swizzled SOURCE col (phys slot p holds logical p^(row&7)).
    int srow = wid * 8 + (lane >> 3);
    int lincol = (lane & 7) * 8;
    int swcol  = ((lane & 7) ^ ((lane >> 3) & 7)) * 8;
    // read-side: k-slot byte offset XOR (row&7)<<4; row&7 == col&7 for all frags.
    int xorv = (col & 7) << 4;
    int ke0 = ((quad * 16) ^ xorv) >> 1;
    int ke1 = ((quad * 16 + 64) ^ xorv) >> 1;

    f4 acc[4][4];
    #pragma unroll
    for (int mi = 0; mi < 4; ++mi)
        #pragma unroll
        for (int ni = 0; ni < 4; ++ni)
            acc[mi][ni] = (f4){0.f, 0.f, 0.f, 0.f};

    #define STG_HALF(mat, rb, ld, ts, dstb) do {                                \
        _Pragma("unroll")                                                       \
        for (int _i = 0; _i < 2; ++_i)                                          \
            stage16((mat) + (long)((rb) + _i * 64 + srow) * (ld) + (ts) * 64 + swcol, \
                    (dstb) + (_i * 64 + srow) * 64 + lincol);                   \
    } while (0)
    #define STGA(ts) STG_HALF(A, m0, lda, (ts), Asl + ((ts) & 1) * 8192)
    #define STGB(ts) do { bf16* _d = Bsl + ((ts) & 1) * 16384;                  \
        STG_HALF(Bt, n0,       ldb, (ts), _d);                                  \
        STG_HALF(Bt, n0 + 128, ldb, (ts), _d + 8192); } while (0)

    bf16x8 a[2][2], bb[4][2];
    #define RD_A(mp) do { _Pragma("unroll")                                     \
        for (int _m = 0; _m < 2; ++_m) {                                        \
            int _r = ab + ((mp) * 2 + _m) * 1024;                               \
            a[_m][0] = *(const bf16x8*)&Asl[_r + ke0];                          \
            a[_m][1] = *(const bf16x8*)&Asl[_r + ke1]; } } while (0)
    #define RD_B(np) do { _Pragma("unroll")                                     \
        for (int _n = 0; _n < 2; ++_n) {                                        \
            int _r = bbo + ((np) * 2 + _n) * 1024;                              \
            bb[(np)*2+_n][0] = *(const bf16x8*)&Bsl[_r + ke0];                  \
            bb[(np)*2+_n][1] = *(const bf16x8*)&Bsl[_r + ke1]; } } while (0)
    #define MM(mp, np) do { __builtin_amdgcn_s_setprio(1);                      \
        _Pragma("unroll")                                                       \
        for (int _m = 0; _m < 2; ++_m)                                          \
            _Pragma("unroll")                                                   \
            for (int _n = 0; _n < 2; ++_n)                                      \
                _Pragma("unroll")                                               \
                for (int kk = 0; kk < 2; ++kk)                                  \
                    acc[(mp)*2+_m][(np)*2+_n] =                                 \
                        __builtin_amdgcn_mfma_f32_16x16x32_bf16(                \
                            a[_m][kk], bb[(np)*2+_n][kk],                       \
                            acc[(mp)*2+_m][(np)*2+_n], 0, 0, 0);                \
        __builtin_amdgcn_s_setprio(0); } while (0)

    // prologue: tiles 0,1 staged (12 ops); oldest 6 (tile 0) landed; barrier.
    STGB(0); STGA(0); STGB(1); STGA(1);
    VMW6; CLOB; BARR; CLOB;

    for (int t = 0; t < NT; ++t) {
        int b = t & 1;
        int ab  = b * 8192  + (wm * 64 + col) * 64;
        int bbo = b * 16384 + (wn * 64 + col) * 64;
        // p1: reads A01+B01; MFMA quad (0,0)
        RD_A(0); RD_B(0);
        CLOB; BARR; SB0; MM(0, 0); CLOB; BARR;
        // p2: reads B23; quad (0,1).  (all B reads of tile t done at end-bar)
        RD_B(1);
        CLOB; BARR; SB0; MM(0, 1); CLOB; BARR;
        // p3: reads A23; stage B(t+2) into freed B region; quad (1,1)
        RD_A(1);
        if (t + 2 < NT) STGB(t + 2);
        CLOB; BARR; SB0; MM(1, 1); CLOB; BARR;
        // p4: stage A(t+2); vmcnt(6) == tile t+1 fully landed (all waves
        // once past the barrier); quad (1,0) reuses live regs.
        if (t + 2 < NT) { STGA(t + 2); VMW6; }
        else if (t + 1 < NT) { VMW0; }
        CLOB; BARR; SB0; MM(1, 0); CLOB; BARR;
    }
    #undef STG_HALF
    #undef STGA
    #undef STGB
    #undef RD_A
    #undef RD_B
    #undef MM

    #pragma unroll
    for (int mi = 0; mi < 4; ++mi) {
        int rbase = m0 + wm * 64 + mi * 16 + quad * 4;
        #pragma unroll
        for (int ni = 0; ni < 4; ++ni) {
            int cc = n0 + wn * 64 + ni * 16 + col;
            #pragma unroll
            for (int r = 0; r < 4; ++r)
                C[(long)(rbase + r) * ldc + cc] = (OutT)acc[mi][ni][r];
        }
    }
}

// ---------------- MFMA flash attention, v6 (verified R12 structure) -------
#define QS 72
#define C_SL 0.18033688011112042f   // 0.125 * log2(e)

__device__ __forceinline__ int vsw(int d, int k) {
    return d * 64 + ((((k >> 3) ^ (d & 7) ^ ((d >> 3) & 7)) & 7) << 3) + (k & 7);
}

__global__ __launch_bounds__(256)
void attn_mfma(bf16* __restrict__ qkv)
{
    __shared__ bf16 Ks[64 * QS];        //  9.2 KB
    __shared__ bf16 Vt[64 * 64];        //  8.0 KB (swizzled)
    __shared__ bf16 Ps[4 * 32 * QS];    // 18.4 KB
    const int T = 2048, D3 = 3072;
    int tid = threadIdx.x;
    int lane = tid & 63, wid = tid >> 6;
    int quad = lane >> 4, col = lane & 15;
    int bh = blockIdx.x & 63;
    int qt = 15 - (blockIdx.x >> 6);     // heavy tiles dispatched first
    int b = bh >> 4, h = bh & 15;
    long base = (long)b * T * D3 + h * 64;
    int q0 = qt * 128;
    int nk = 2 * qt + 2;
    int srow = tid >> 2, dseg = (tid & 3) * 16;   // 64x64 staging map
    bf16* Pw = &Ps[wid * 32 * QS];

    // Q B-frags (held in regs): lane holds Q[q=nt*16+col][d=quad*8+j+32*ch]
    bf16x8 aq[2][2];
    #pragma unroll
    for (int nt = 0; nt < 2; ++nt) {
        const bf16* gq = &qkv[base + (long)(q0 + wid * 32 + nt * 16 + col) * D3 + quad * 8];
        aq[nt][0] = *(const bf16x8*)gq;
        aq[nt][1] = *(const bf16x8*)(gq + 32);
    }
    bf16 one1 = (bf16)1.0f;
    bf16x8 bones = {one1, one1, one1, one1, one1, one1, one1, one1};

    f4 of[2][4], lac[2];
    #pragma unroll
    for (int mg = 0; mg < 2; ++mg) {
        lac[mg] = (f4){0.f, 0.f, 0.f, 0.f};
        #pragma unroll
        for (int n = 0; n < 4; ++n) of[mg][n] = (f4){0.f, 0.f, 0.f, 0.f};
    }

    // prefetch k-tile 0
    const bf16* g0 = &qkv[base + (long)srow * D3 + 1024 + dseg];
    bf16x8 kr0 = *(const bf16x8*)g0;
    bf16x8 kr1 = *(const bf16x8*)(g0 + 8);
    bf16x8 vr0 = *(const bf16x8*)(g0 + 1024);
    bf16x8 vr1 = *(const bf16x8*)(g0 + 1032);

    for (int kt = 0; kt < nk; ++kt) {
        __syncthreads();                 // prior iter's LDS reads done
        *(bf16x8*)&Ks[srow * QS + dseg]     = kr0;
        *(bf16x8*)&Ks[srow * QS + dseg + 8] = kr1;
        #pragma unroll
        for (int j = 0; j < 8; ++j) {
            Vt[vsw(dseg + j, srow)]     = vr0[j];
            Vt[vsw(dseg + 8 + j, srow)] = vr1[j];
        }
        if (kt + 1 < nk) {               // latency hidden behind compute
            const bf16* gn = &qkv[base + (long)((kt + 1) * 64 + srow) * D3 + 1024 + dseg];
            kr0 = *(const bf16x8*)gn;
            kr1 = *(const bf16x8*)(gn + 8);
            vr0 = *(const bf16x8*)(gn + 1024);
            vr1 = *(const bf16x8*)(gn + 1032);
        }
        __syncthreads();
        // S^T = K Q^T, fused per 16-row k-chunk (bounds live registers)
        bool diag = (kt >= nk - 2);
        int k0 = kt * 64;
        #pragma unroll
        for (int mt = 0; mt < 4; ++mt) {
            bf16x8 ak0 = *(const bf16x8*)&Ks[(mt * 16 + col) * QS + quad * 8];
            bf16x8 ak1 = *(const bf16x8*)&Ks[(mt * 16 + col) * QS + 32 + quad * 8];
            #pragma unroll
            for (int nt = 0; nt < 2; ++nt) {
                f4 z = (f4){0.f, 0.f, 0.f, 0.f};
                __builtin_amdgcn_s_setprio(1);
                z = __builtin_amdgcn_mfma_f32_16x16x32_bf16(ak0, aq[nt][0], z, 0, 0, 0);
                f4 st = __builtin_amdgcn_mfma_f32_16x16x32_bf16(ak1, aq[nt][1], z, 0, 0, 0);
                __builtin_amdgcn_s_setprio(0);
                bf16x4 pk;
                if (diag) {
                    int qg = q0 + wid * 32 + nt * 16 + col;
                    #pragma unroll
                    for (int r = 0; r < 4; ++r) {
                        float arg = fmaf(st[r], C_SL, -16.f);
                        if ((k0 + mt * 16 + quad * 4 + r) > qg) arg = -1e30f;
                        pk[r] = (bf16)exp2f(arg);
                    }
                } else {
                    #pragma unroll
                    for (int r = 0; r < 4; ++r)
                        pk[r] = (bf16)exp2f(fmaf(st[r], C_SL, -16.f));
                }
                *(bf16x4*)&Pw[(nt * 16 + col) * QS + mt * 16 + quad * 4] = pk;
            }
        }
        // P readback (wave-private, no barrier): hoisted A-frags
        bf16x8 ap[2][2];
        #pragma unroll
        for (int mg = 0; mg < 2; ++mg) {
            ap[mg][0] = *(const bf16x8*)&Pw[(mg * 16 + col) * QS + quad * 8];
            ap[mg][1] = *(const bf16x8*)&Pw[(mg * 16 + col) * QS + 32 + quad * 8];
        }
        // O += P V: nd-major so each V frag pair is read ONCE (8 b128/iter)
        #pragma unroll
        for (int nd = 0; nd < 4; ++nd) {
            bf16x8 bv0 = *(const bf16x8*)&Vt[vsw(nd * 16 + col, quad * 8)];
            bf16x8 bv1 = *(const bf16x8*)&Vt[vsw(nd * 16 + col, 32 + quad * 8)];
            __builtin_amdgcn_s_setprio(1);
            of[0][nd] = __builtin_amdgcn_mfma_f32_16x16x32_bf16(ap[0][0], bv0, of[0][nd], 0, 0, 0);
            of[0][nd] = __builtin_amdgcn_mfma_f32_16x16x32_bf16(ap[0][1], bv1, of[0][nd], 0, 0, 0);
            of[1][nd] = __builtin_amdgcn_mfma_f32_16x16x32_bf16(ap[1][0], bv0, of[1][nd], 0, 0, 0);
            of[1][nd] = __builtin_amdgcn_mfma_f32_16x16x32_bf16(ap[1][1], bv1, of[1][nd], 0, 0, 0);
            __builtin_amdgcn_s_setprio(0);
        }
        // l += P 1
        __builtin_amdgcn_s_setprio(1);
        #pragma unroll
        for (int mg = 0; mg < 2; ++mg) {
            lac[mg] = __builtin_amdgcn_mfma_f32_16x16x32_bf16(ap[mg][0], bones, lac[mg], 0, 0, 0);
            lac[mg] = __builtin_amdgcn_mfma_f32_16x16x32_bf16(ap[mg][1], bones, lac[mg], 0, 0, 0);
        }
        __builtin_amdgcn_s_setprio(0);
    }
    // epilogue: y into this block's dead Q region; l is in O's C-layout
    #pragma unroll
    for (int mg = 0; mg < 2; ++mg)
        #pragma unroll
        for (int r = 0; r < 4; ++r) {
            float inv = 1.f / lac[mg][r];
            long yoff = base + (long)(q0 + wid * 32 + mg * 16 + quad * 4 + r) * D3;
            #pragma unroll
            for (int nd = 0; nd < 4; ++nd)
                qkv[yoff + nd * 16 + col] = (bf16)(of[mg][nd][r] * inv);
        }
}

// --------------------------------------------------------------------------
extern "C" void kernel_launch(void* const* d_in, const int* in_sizes, int n_in,
                              void* d_out, int out_size, void* d_ws, size_t ws_size,
                              hipStream_t stream) {
    const float* x      = (const float*)d_in[0];  // [8192,1024] fp32
    const float* W_attn = (const float*)d_in[1];  // [1024,3072] fp32
    const float* W_proj = (const float*)d_in[2];  // [1024,1024] fp32
    float* out = (float*)d_out;                   // [8192,1024] fp32

    // ws layout (58.7 MB): qkv | WtA | WtP
    bf16* qkv = (bf16*)d_ws;                         // [8192,3072]  50.3 MB
    bf16* WtA = qkv + (size_t)8192 * 3072;           // [3072,1024]   6.3 MB
    bf16* WtP = WtA + (size_t)3072 * 1024;           // [1024,1024]   2.1 MB
    bf16* xb = (bf16*)d_out;   // bf16 x staged in d_out; dead before gemm2

    static bool attr_set = false;
    if (!attr_set) {
        hipFuncSetAttribute((const void*)gemm256<bf16>,
                            hipFuncAttributeMaxDynamicSharedMemorySize, 98304);
        hipFuncSetAttribute((const void*)gemm256<float>,
                            hipFuncAttributeMaxDynamicSharedMemorySize, 98304);
        attr_set = true;
    }

    cast_f32_bf16<<<8192, 256, 0, stream>>>(x, xb, 8192 * 1024 / 4);
    transpose_f32_bf16<<<dim3(48, 16), 256, 0, stream>>>(W_attn, WtA, 1024, 3072);
    transpose_f32_bf16<<<dim3(16, 16), 256, 0, stream>>>(W_proj, WtP, 1024, 1024);
    // qkv = xb @ W_attn  (bf16 out): 128x256 tiles, grid 12x64 = 768 = 3*256
    gemm256<bf16><<<dim3(12, 64), 512, 98304, stream>>>(xb, WtA, qkv,
                                                        1024, 1024, 3072, 1024);
    // MFMA flash attention; y written into qkv's Q columns
    attn_mfma<<<1024, 256, 0, stream>>>(qkv);
    // out = y @ W_proj: 128x256 tiles, grid 4x64 = 256 = exactly 1 wave
    gemm256<float><<<dim3(4, 64), 512, 98304, stream>>>(qkv, WtP, out,
                                                        3072, 1024, 1024, 1024);
}

// Round 8
// 250.319 us; speedup vs baseline: 1.1302x; 1.0210x over previous
//
#include <hip/hip_runtime.h>

// B=4, T=2048, D=1024, H=16, hd=64. Inputs/output fp32; internal bf16 MFMA.
// R18: two independent changes.
// (1) gemm256: 4 thin phases (8 MFMA/barrier-pair, 8 barriers/K-tile) ->
//     2 fat phases (16 MFMA/barrier-pair, 4 barriers/K-tile), m201 grain.
//     p1{rdA0+rdB01+B23 | bar | MM(0,*) | bar}
//     p2{rdA1+stgB(t+2) | bar | MM(1,*)+stgA(t+2)+vmcnt6 | bar}.
//     WAR: stgB after p1-end bar (B reads done); stgA issued post-MM, its
//     LDS write returns >=200cy after all waves' RD_A(1) executed.
// (2) attn: V staging 16 scalar vsw-scatter stores (~70 VALU addr ops/iter)
//     -> 4x4 in-register transpose + 4 bf16x4 stores (R13-verified path,
//     ~20 VALU), same vsw layout, read side untouched.

typedef __bf16 bf16;
typedef __attribute__((ext_vector_type(8))) __bf16 bf16x8;
typedef __attribute__((ext_vector_type(4))) __bf16 bf16x4;
typedef __attribute__((ext_vector_type(4))) float f4;

__device__ __forceinline__ void stage16(const bf16* g, bf16* l) {
    __builtin_amdgcn_global_load_lds((const __attribute__((address_space(1))) void*)g,
                                     (__attribute__((address_space(3))) void*)l,
                                     16, 0, 0);
}

// ---------------- cast fp32 -> bf16, vectorized ---------------------------
__global__ __launch_bounds__(256)
void cast_f32_bf16(const float* __restrict__ src, bf16* __restrict__ dst, int n4)
{
    int i = blockIdx.x * 256 + threadIdx.x;
    if (i < n4) {
        float4 v = ((const float4*)src)[i];
        bf16x4 o = { (bf16)v.x, (bf16)v.y, (bf16)v.z, (bf16)v.w };
        *(bf16x4*)&dst[i * 4] = o;
    }
}

// ---------------- transpose + cast: fp32 src [R][C] -> bf16 dst [C][R] ----
__global__ __launch_bounds__(256)
void transpose_f32_bf16(const float* __restrict__ src, bf16* __restrict__ dst,
                        int R, int C)
{
    __shared__ bf16 tile[64][65];
    int c0 = blockIdx.x * 64, r0 = blockIdx.y * 64;
    int tid = threadIdx.x;
    for (int i = tid; i < 64 * 64; i += 256) {
        int r = i >> 6, c = i & 63;
        tile[r][c] = (bf16)src[(long)(r0 + r) * C + c0 + c];
    }
    __syncthreads();
    for (int i = tid; i < 64 * 64; i += 256) {
        int r = i >> 6, c = i & 63;
        dst[(long)(c0 + r) * R + r0 + c] = tile[c][r];
    }
}

// ---------------- GEMM 128x256 2-fat-phase (T1+T2+T3+T4+T5) ---------------
// C[M,N] = A[M,K] x Bt[N,K]^T; strides lda/ldb/ldc explicit. 512 thr =
// 8 waves (2M x 4N); per-wave 64x64 out. BK=64; LDS 96KB: Asl[2][128][64],
// Bsl[2][256][64]; 16B-granule involution swizzle via pre-swizzled global
// source col (LDS dest linear), reads XOR k-slot bytes with (col&7)<<4.
#define VMW6 asm volatile("s_waitcnt vmcnt(6)" ::: "memory")
#define VMW0 asm volatile("s_waitcnt vmcnt(0)" ::: "memory")
#define CLOB asm volatile("" ::: "memory")
#define BARR __builtin_amdgcn_s_barrier()
#define SB0  __builtin_amdgcn_sched_barrier(0)

template <typename OutT>
__global__ __launch_bounds__(512)
void gemm256(const bf16* __restrict__ A, const bf16* __restrict__ Bt,
             OutT* __restrict__ C, int lda, int ldb, int ldc, int K)
{
    extern __shared__ bf16 lds[];
    bf16* Asl = lds;                  // [2][128][64]
    bf16* Bsl = lds + 16384;          // [2][256][64]
    int tid = threadIdx.x;
    int lane = tid & 63, wid = tid >> 6;
    int wm = wid >> 2, wn = wid & 3;
    int quad = lane >> 4, col = lane & 15;

    int nwg = gridDim.x * gridDim.y;
    int bid = blockIdx.y * gridDim.x + blockIdx.x;
    int swz = (bid & 7) * (nwg >> 3) + (bid >> 3);
    int bx = swz % gridDim.x, by = swz / gridDim.x;
    int m0 = by * 128, n0 = bx * 256;

    int NT = K >> 6;
    int srow = wid * 8 + (lane >> 3);
    int lincol = (lane & 7) * 8;
    int swcol  = ((lane & 7) ^ ((lane >> 3) & 7)) * 8;
    int xorv = (col & 7) << 4;
    int ke0 = ((quad * 16) ^ xorv) >> 1;
    int ke1 = ((quad * 16 + 64) ^ xorv) >> 1;

    f4 acc[4][4];
    #pragma unroll
    for (int mi = 0; mi < 4; ++mi)
        #pragma unroll
        for (int ni = 0; ni < 4; ++ni)
            acc[mi][ni] = (f4){0.f, 0.f, 0.f, 0.f};

    #define STG_HALF(mat, rb, ld, ts, dstb) do {                                \
        _Pragma("unroll")                                                       \
        for (int _i = 0; _i < 2; ++_i)                                          \
            stage16((mat) + (long)((rb) + _i * 64 + srow) * (ld) + (ts) * 64 + swcol, \
                    (dstb) + (_i * 64 + srow) * 64 + lincol);                   \
    } while (0)
    #define STGA(ts) STG_HALF(A, m0, lda, (ts), Asl + ((ts) & 1) * 8192)
    #define STGB(ts) do { bf16* _d = Bsl + ((ts) & 1) * 16384;                  \
        STG_HALF(Bt, n0,       ldb, (ts), _d);                                  \
        STG_HALF(Bt, n0 + 128, ldb, (ts), _d + 8192); } while (0)

    bf16x8 a[2][2], bb[4][2];
    #define RD_A(mp) do { _Pragma("unroll")                                     \
        for (int _m = 0; _m < 2; ++_m) {                                        \
            int _r = ab + ((mp) * 2 + _m) * 1024;                               \
            a[_m][0] = *(const bf16x8*)&Asl[_r + ke0];                          \
            a[_m][1] = *(const bf16x8*)&Asl[_r + ke1]; } } while (0)
    #define RD_B(np) do { _Pragma("unroll")                                     \
        for (int _n = 0; _n < 2; ++_n) {                                        \
            int _r = bbo + ((np) * 2 + _n) * 1024;                              \
            bb[(np)*2+_n][0] = *(const bf16x8*)&Bsl[_r + ke0];                  \
            bb[(np)*2+_n][1] = *(const bf16x8*)&Bsl[_r + ke1]; } } while (0)
    #define MM(mp, np) do { __builtin_amdgcn_s_setprio(1);                      \
        _Pragma("unroll")                                                       \
        for (int _m = 0; _m < 2; ++_m)                                          \
            _Pragma("unroll")                                                   \
            for (int _n = 0; _n < 2; ++_n)                                      \
                _Pragma("unroll")                                               \
                for (int kk = 0; kk < 2; ++kk)                                  \
                    acc[(mp)*2+_m][(np)*2+_n] =                                 \
                        __builtin_amdgcn_mfma_f32_16x16x32_bf16(                \
                            a[_m][kk], bb[(np)*2+_n][kk],                       \
                            acc[(mp)*2+_m][(np)*2+_n], 0, 0, 0);                \
        __builtin_amdgcn_s_setprio(0); } while (0)

    // prologue: tiles 0,1 staged (12 loads/thread); tile 0 landed; barrier.
    STGB(0); STGA(0); STGB(1); STGA(1);
    VMW6; CLOB; BARR; CLOB;

    for (int t = 0; t < NT; ++t) {
        int b = t & 1;
        int ab  = b * 8192  + (wm * 64 + col) * 64;
        int bbo = b * 16384 + (wn * 64 + col) * 64;
        // p1: read A-low + ALL B frags; 16 MFMAs
        RD_A(0); RD_B(0); RD_B(1);
        CLOB; BARR; SB0; MM(0, 0); MM(0, 1); CLOB; BARR;
        // p2: read A-high; stage B(t+2) (B reads done at p1-end barrier);
        //     16 MFMAs; stage A(t+2) + vmcnt(6) (tile t+1 landed for all
        //     waves once past the final barrier).
        RD_A(1);
        if (t + 2 < NT) STGB(t + 2);
        CLOB; BARR; SB0; MM(1, 1); MM(1, 0);
        if (t + 2 < NT) { STGA(t + 2); VMW6; }
        else if (t + 1 < NT) { VMW0; }
        CLOB; BARR;
    }
    #undef STG_HALF
    #undef STGA
    #undef STGB
    #undef RD_A
    #undef RD_B
    #undef MM

    #pragma unroll
    for (int mi = 0; mi < 4; ++mi) {
        int rbase = m0 + wm * 64 + mi * 16 + quad * 4;
        #pragma unroll
        for (int ni = 0; ni < 4; ++ni) {
            int cc = n0 + wn * 64 + ni * 16 + col;
            #pragma unroll
            for (int r = 0; r < 4; ++r)
                C[(long)(rbase + r) * ldc + cc] = (OutT)acc[mi][ni][r];
        }
    }
}

// ---------------- MFMA flash attention, v9 (R12 + reg-transposed V stage) -
#define QS 72
#define C_SL 0.18033688011112042f   // 0.125 * log2(e)

__device__ __forceinline__ int vsw(int d, int k) {
    return d * 64 + ((((k >> 3) ^ (d & 7) ^ ((d >> 3) & 7)) & 7) << 3) + (k & 7);
}

__global__ __launch_bounds__(256)
void attn_mfma(bf16* __restrict__ qkv)
{
    __shared__ bf16 Ks[64 * QS];        //  9.2 KB
    __shared__ bf16 Vt[64 * 64];        //  8.0 KB (vsw-swizzled)
    __shared__ bf16 Ps[4 * 32 * QS];    // 18.4 KB
    const int T = 2048, D3 = 3072;
    int tid = threadIdx.x;
    int lane = tid & 63, wid = tid >> 6;
    int quad = lane >> 4, col = lane & 15;
    int bh = blockIdx.x & 63;
    int qt = 15 - (blockIdx.x >> 6);     // heavy tiles dispatched first
    int b = bh >> 4, h = bh & 15;
    long base = (long)b * T * D3 + h * 64;
    int q0 = qt * 128;
    int nk = 2 * qt + 2;
    int srow = tid >> 2, dseg = (tid & 3) * 16;   // K staging map (64x64)
    int kg4 = (tid >> 4) * 4, dg4 = (tid & 15) * 4; // V staging map (4k x 4d)
    bf16* Pw = &Ps[wid * 32 * QS];

    // Q B-frags (held in regs): lane holds Q[q=nt*16+col][d=quad*8+j+32*ch]
    bf16x8 aq[2][2];
    #pragma unroll
    for (int nt = 0; nt < 2; ++nt) {
        const bf16* gq = &qkv[base + (long)(q0 + wid * 32 + nt * 16 + col) * D3 + quad * 8];
        aq[nt][0] = *(const bf16x8*)gq;
        aq[nt][1] = *(const bf16x8*)(gq + 32);
    }
    bf16 one1 = (bf16)1.0f;
    bf16x8 bones = {one1, one1, one1, one1, one1, one1, one1, one1};

    f4 of[2][4], lac[2];
    #pragma unroll
    for (int mg = 0; mg < 2; ++mg) {
        lac[mg] = (f4){0.f, 0.f, 0.f, 0.f};
        #pragma unroll
        for (int n = 0; n < 4; ++n) of[mg][n] = (f4){0.f, 0.f, 0.f, 0.f};
    }

    // prefetch k-tile 0
    const bf16* g0 = &qkv[base + (long)srow * D3 + 1024 + dseg];
    bf16x8 kr0 = *(const bf16x8*)g0;
    bf16x8 kr1 = *(const bf16x8*)(g0 + 8);
    const bf16* gV = &qkv[base + (long)kg4 * D3 + 2048 + dg4];
    bf16x4 vr[4];
    #pragma unroll
    for (int j = 0; j < 4; ++j) vr[j] = *(const bf16x4*)(gV + (long)j * D3);

    for (int kt = 0; kt < nk; ++kt) {
        __syncthreads();                 // prior iter's LDS reads done
        *(bf16x8*)&Ks[srow * QS + dseg]     = kr0;
        *(bf16x8*)&Ks[srow * QS + dseg + 8] = kr1;
        #pragma unroll
        for (int i = 0; i < 4; ++i) {    // 4x4 in-register transpose (R13)
            bf16x4 c = { vr[0][i], vr[1][i], vr[2][i], vr[3][i] };
            *(bf16x4*)&Vt[vsw(dg4 + i, kg4)] = c;
        }
        if (kt + 1 < nk) {               // latency hidden behind compute
            const bf16* gKn = &qkv[base + (long)((kt + 1) * 64 + srow) * D3 + 1024 + dseg];
            kr0 = *(const bf16x8*)gKn;
            kr1 = *(const bf16x8*)(gKn + 8);
            const bf16* gVn = &qkv[base + (long)((kt + 1) * 64 + kg4) * D3 + 2048 + dg4];
            #pragma unroll
            for (int j = 0; j < 4; ++j) vr[j] = *(const bf16x4*)(gVn + (long)j * D3);
        }
        __syncthreads();
        // S^T = K Q^T, fused per 16-row k-chunk (bounds live registers)
        bool diag = (kt >= nk - 2);
        int k0 = kt * 64;
        #pragma unroll
        for (int mt = 0; mt < 4; ++mt) {
            bf16x8 ak0 = *(const bf16x8*)&Ks[(mt * 16 + col) * QS + quad * 8];
            bf16x8 ak1 = *(const bf16x8*)&Ks[(mt * 16 + col) * QS + 32 + quad * 8];
            #pragma unroll
            for (int nt = 0; nt < 2; ++nt) {
                f4 z = (f4){0.f, 0.f, 0.f, 0.f};
                __builtin_amdgcn_s_setprio(1);
                z = __builtin_amdgcn_mfma_f32_16x16x32_bf16(ak0, aq[nt][0], z, 0, 0, 0);
                f4 st = __builtin_amdgcn_mfma_f32_16x16x32_bf16(ak1, aq[nt][1], z, 0, 0, 0);
                __builtin_amdgcn_s_setprio(0);
                bf16x4 pk;
                if (diag) {
                    int qg = q0 + wid * 32 + nt * 16 + col;
                    #pragma unroll
                    for (int r = 0; r < 4; ++r) {
                        float arg = fmaf(st[r], C_SL, -16.f);
                        if ((k0 + mt * 16 + quad * 4 + r) > qg) arg = -1e30f;
                        pk[r] = (bf16)exp2f(arg);
                    }
                } else {
                    #pragma unroll
                    for (int r = 0; r < 4; ++r)
                        pk[r] = (bf16)exp2f(fmaf(st[r], C_SL, -16.f));
                }
                *(bf16x4*)&Pw[(nt * 16 + col) * QS + mt * 16 + quad * 4] = pk;
            }
        }
        // P readback (wave-private, no barrier): hoisted A-frags
        bf16x8 ap[2][2];
        #pragma unroll
        for (int mg = 0; mg < 2; ++mg) {
            ap[mg][0] = *(const bf16x8*)&Pw[(mg * 16 + col) * QS + quad * 8];
            ap[mg][1] = *(const bf16x8*)&Pw[(mg * 16 + col) * QS + 32 + quad * 8];
        }
        // O += P V: nd-major so each V frag pair is read ONCE (8 b128/iter)
        #pragma unroll
        for (int nd = 0; nd < 4; ++nd) {
            bf16x8 bv0 = *(const bf16x8*)&Vt[vsw(nd * 16 + col, quad * 8)];
            bf16x8 bv1 = *(const bf16x8*)&Vt[vsw(nd * 16 + col, 32 + quad * 8)];
            __builtin_amdgcn_s_setprio(1);
            of[0][nd] = __builtin_amdgcn_mfma_f32_16x16x32_bf16(ap[0][0], bv0, of[0][nd], 0, 0, 0);
            of[0][nd] = __builtin_amdgcn_mfma_f32_16x16x32_bf16(ap[0][1], bv1, of[0][nd], 0, 0, 0);
            of[1][nd] = __builtin_amdgcn_mfma_f32_16x16x32_bf16(ap[1][0], bv0, of[1][nd], 0, 0, 0);
            of[1][nd] = __builtin_amdgcn_mfma_f32_16x16x32_bf16(ap[1][1], bv1, of[1][nd], 0, 0, 0);
            __builtin_amdgcn_s_setprio(0);
        }
        // l += P 1
        __builtin_amdgcn_s_setprio(1);
        #pragma unroll
        for (int mg = 0; mg < 2; ++mg) {
            lac[mg] = __builtin_amdgcn_mfma_f32_16x16x32_bf16(ap[mg][0], bones, lac[mg], 0, 0, 0);
            lac[mg] = __builtin_amdgcn_mfma_f32_16x16x32_bf16(ap[mg][1], bones, lac[mg], 0, 0, 0);
        }
        __builtin_amdgcn_s_setprio(0);
    }
    // epilogue: y into this block's dead Q region; l is in O's C-layout
    #pragma unroll
    for (int mg = 0; mg < 2; ++mg)
        #pragma unroll
        for (int r = 0; r < 4; ++r) {
            float inv = 1.f / lac[mg][r];
            long yoff = base + (long)(q0 + wid * 32 + mg * 16 + quad * 4 + r) * D3;
            #pragma unroll
            for (int nd = 0; nd < 4; ++nd)
                qkv[yoff + nd * 16 + col] = (bf16)(of[mg][nd][r] * inv);
        }
}

// --------------------------------------------------------------------------
extern "C" void kernel_launch(void* const* d_in, const int* in_sizes, int n_in,
                              void* d_out, int out_size, void* d_ws, size_t ws_size,
                              hipStream_t stream) {
    const float* x      = (const float*)d_in[0];  // [8192,1024] fp32
    const float* W_attn = (const float*)d_in[1];  // [1024,3072] fp32
    const float* W_proj = (const float*)d_in[2];  // [1024,1024] fp32
    float* out = (float*)d_out;                   // [8192,1024] fp32

    // ws layout (58.7 MB): qkv | WtA | WtP
    bf16* qkv = (bf16*)d_ws;                         // [8192,3072]  50.3 MB
    bf16* WtA = qkv + (size_t)8192 * 3072;           // [3072,1024]   6.3 MB
    bf16* WtP = WtA + (size_t)3072 * 1024;           // [1024,1024]   2.1 MB
    bf16* xb = (bf16*)d_out;   // bf16 x staged in d_out; dead before gemm2

    static bool attr_set = false;
    if (!attr_set) {
        hipFuncSetAttribute((const void*)gemm256<bf16>,
                            hipFuncAttributeMaxDynamicSharedMemorySize, 98304);
        hipFuncSetAttribute((const void*)gemm256<float>,
                            hipFuncAttributeMaxDynamicSharedMemorySize, 98304);
        attr_set = true;
    }

    cast_f32_bf16<<<8192, 256, 0, stream>>>(x, xb, 8192 * 1024 / 4);
    transpose_f32_bf16<<<dim3(48, 16), 256, 0, stream>>>(W_attn, WtA, 1024, 3072);
    transpose_f32_bf16<<<dim3(16, 16), 256, 0, stream>>>(W_proj, WtP, 1024, 1024);
    // qkv = xb @ W_attn  (bf16 out): 128x256 tiles, grid 12x64 = 768 = 3*256
    gemm256<bf16><<<dim3(12, 64), 512, 98304, stream>>>(xb, WtA, qkv,
                                                        1024, 1024, 3072, 1024);
    // MFMA flash attention; y written into qkv's Q columns
    attn_mfma<<<1024, 256, 0, stream>>>(qkv);
    // out = y @ W_proj: 128x256 tiles, grid 4x64 = 256 = exactly 1 wave
    gemm256<float><<<dim3(4, 64), 512, 98304, stream>>>(qkv, WtP, out,
                                                        3072, 1024, 1024, 1024);
}

// Round 9
// 239.412 us; speedup vs baseline: 1.1817x; 1.0456x over previous
//
#include <hip/hip_runtime.h>

// B=4, T=2048, D=1024, H=16, hd=64. Inputs/output fp32; internal bf16 MFMA.
// R19: two changes driven by the accounting anomaly + attn VALU budget.
// (1) LAUNCH-GAP CUT: kernel-time sums trail the measured total by a stable
//     ~73us across rounds (R2: 193 vs 266; R8: 176 vs 250) -> ~12us per
//     launch overhead. Fuse cast + both weight transposes into ONE prep
//     kernel (blockIdx-range dispatch): 6 launches -> 4, predicted -24us.
// (2) attn exp2f -> raw v_exp_f32 inline asm: 32 transcendentals/wave-iter
//     dominate the 64% VALUBusy; drops the libm wrapper ops (~64-128
//     cyc/iter). Mask arg -1e30 underflows to 0 as required.
// gemms = R8-verified (controls).

typedef __bf16 bf16;
typedef __attribute__((ext_vector_type(8))) __bf16 bf16x8;
typedef __attribute__((ext_vector_type(4))) __bf16 bf16x4;
typedef __attribute__((ext_vector_type(4))) float f4;

__device__ __forceinline__ void stage16(const bf16* g, bf16* l) {
    __builtin_amdgcn_global_load_lds((const __attribute__((address_space(1))) void*)g,
                                     (__attribute__((address_space(3))) void*)l,
                                     16, 0, 0);
}

__device__ __forceinline__ float fast_exp2(float x) {
    float r;
    asm("v_exp_f32 %0, %1" : "=v"(r) : "v"(x));
    return r;
}

// ---------------- fused prep: cast x + transpose both weights -------------
// blocks 0..8191: cast x (fp32->bf16, float4/lane)
// blocks 8192..8959: W_attn [1024][3072] -> WtA [3072][1024]
// blocks 8960..9215: W_proj [1024][1024] -> WtP [1024][1024]
__global__ __launch_bounds__(256)
void prep(const float* __restrict__ x, bf16* __restrict__ xb,
          const float* __restrict__ Wa, bf16* __restrict__ WtA,
          const float* __restrict__ Wp, bf16* __restrict__ WtP)
{
    __shared__ bf16 tile[64][65];
    int bid = blockIdx.x;
    int tid = threadIdx.x;
    if (bid < 8192) {
        int i = bid * 256 + tid;
        float4 v = ((const float4*)x)[i];
        bf16x4 o = { (bf16)v.x, (bf16)v.y, (bf16)v.z, (bf16)v.w };
        *(bf16x4*)&xb[i * 4] = o;
        return;
    }
    const float* src; bf16* dst; int R, C, c0, r0;
    if (bid < 8960) {
        int t = bid - 8192;                // 48 x 16 tiles
        src = Wa; dst = WtA; R = 1024; C = 3072;
        c0 = (t % 48) * 64; r0 = (t / 48) * 64;
    } else {
        int t = bid - 8960;                // 16 x 16 tiles
        src = Wp; dst = WtP; R = 1024; C = 1024;
        c0 = (t % 16) * 64; r0 = (t / 16) * 64;
    }
    for (int i = tid; i < 64 * 64; i += 256) {
        int r = i >> 6, c = i & 63;
        tile[r][c] = (bf16)src[(long)(r0 + r) * C + c0 + c];
    }
    __syncthreads();
    for (int i = tid; i < 64 * 64; i += 256) {
        int r = i >> 6, c = i & 63;
        dst[(long)(c0 + r) * R + r0 + c] = tile[c][r];
    }
}

// ---------------- GEMM 128x256 2-fat-phase (T1+T2+T3+T4+T5) ---------------
// C[M,N] = A[M,K] x Bt[N,K]^T; strides lda/ldb/ldc explicit. 512 thr =
// 8 waves (2M x 4N); per-wave 64x64 out. BK=64; LDS 96KB: Asl[2][128][64],
// Bsl[2][256][64]; 16B-granule involution swizzle via pre-swizzled global
// source col (LDS dest linear), reads XOR k-slot bytes with (col&7)<<4.
#define VMW6 asm volatile("s_waitcnt vmcnt(6)" ::: "memory")
#define VMW0 asm volatile("s_waitcnt vmcnt(0)" ::: "memory")
#define CLOB asm volatile("" ::: "memory")
#define BARR __builtin_amdgcn_s_barrier()
#define SB0  __builtin_amdgcn_sched_barrier(0)

template <typename OutT>
__global__ __launch_bounds__(512)
void gemm256(const bf16* __restrict__ A, const bf16* __restrict__ Bt,
             OutT* __restrict__ C, int lda, int ldb, int ldc, int K)
{
    extern __shared__ bf16 lds[];
    bf16* Asl = lds;                  // [2][128][64]
    bf16* Bsl = lds + 16384;          // [2][256][64]
    int tid = threadIdx.x;
    int lane = tid & 63, wid = tid >> 6;
    int wm = wid >> 2, wn = wid & 3;
    int quad = lane >> 4, col = lane & 15;

    int nwg = gridDim.x * gridDim.y;
    int bid = blockIdx.y * gridDim.x + blockIdx.x;
    int swz = (bid & 7) * (nwg >> 3) + (bid >> 3);
    int bx = swz % gridDim.x, by = swz / gridDim.x;
    int m0 = by * 128, n0 = bx * 256;

    int NT = K >> 6;
    int srow = wid * 8 + (lane >> 3);
    int lincol = (lane & 7) * 8;
    int swcol  = ((lane & 7) ^ ((lane >> 3) & 7)) * 8;
    int xorv = (col & 7) << 4;
    int ke0 = ((quad * 16) ^ xorv) >> 1;
    int ke1 = ((quad * 16 + 64) ^ xorv) >> 1;

    f4 acc[4][4];
    #pragma unroll
    for (int mi = 0; mi < 4; ++mi)
        #pragma unroll
        for (int ni = 0; ni < 4; ++ni)
            acc[mi][ni] = (f4){0.f, 0.f, 0.f, 0.f};

    #define STG_HALF(mat, rb, ld, ts, dstb) do {                                \
        _Pragma("unroll")                                                       \
        for (int _i = 0; _i < 2; ++_i)                                          \
            stage16((mat) + (long)((rb) + _i * 64 + srow) * (ld) + (ts) * 64 + swcol, \
                    (dstb) + (_i * 64 + srow) * 64 + lincol);                   \
    } while (0)
    #define STGA(ts) STG_HALF(A, m0, lda, (ts), Asl + ((ts) & 1) * 8192)
    #define STGB(ts) do { bf16* _d = Bsl + ((ts) & 1) * 16384;                  \
        STG_HALF(Bt, n0,       ldb, (ts), _d);                                  \
        STG_HALF(Bt, n0 + 128, ldb, (ts), _d + 8192); } while (0)

    bf16x8 a[2][2], bb[4][2];
    #define RD_A(mp) do { _Pragma("unroll")                                     \
        for (int _m = 0; _m < 2; ++_m) {                                        \
            int _r = ab + ((mp) * 2 + _m) * 1024;                               \
            a[_m][0] = *(const bf16x8*)&Asl[_r + ke0];                          \
            a[_m][1] = *(const bf16x8*)&Asl[_r + ke1]; } } while (0)
    #define RD_B(np) do { _Pragma("unroll")                                     \
        for (int _n = 0; _n < 2; ++_n) {                                        \
            int _r = bbo + ((np) * 2 + _n) * 1024;                              \
            bb[(np)*2+_n][0] = *(const bf16x8*)&Bsl[_r + ke0];                  \
            bb[(np)*2+_n][1] = *(const bf16x8*)&Bsl[_r + ke1]; } } while (0)
    #define MM(mp, np) do { __builtin_amdgcn_s_setprio(1);                      \
        _Pragma("unroll")                                                       \
        for (int _m = 0; _m < 2; ++_m)                                          \
            _Pragma("unroll")                                                   \
            for (int _n = 0; _n < 2; ++_n)                                      \
                _Pragma("unroll")                                               \
                for (int kk = 0; kk < 2; ++kk)                                  \
                    acc[(mp)*2+_m][(np)*2+_n] =                                 \
                        __builtin_amdgcn_mfma_f32_16x16x32_bf16(                \
                            a[_m][kk], bb[(np)*2+_n][kk],                       \
                            acc[(mp)*2+_m][(np)*2+_n], 0, 0, 0);                \
        __builtin_amdgcn_s_setprio(0); } while (0)

    // prologue: tiles 0,1 staged (12 loads/thread); tile 0 landed; barrier.
    STGB(0); STGA(0); STGB(1); STGA(1);
    VMW6; CLOB; BARR; CLOB;

    for (int t = 0; t < NT; ++t) {
        int b = t & 1;
        int ab  = b * 8192  + (wm * 64 + col) * 64;
        int bbo = b * 16384 + (wn * 64 + col) * 64;
        // p1: read A-low + ALL B frags; 16 MFMAs
        RD_A(0); RD_B(0); RD_B(1);
        CLOB; BARR; SB0; MM(0, 0); MM(0, 1); CLOB; BARR;
        // p2: read A-high; stage B(t+2) (B reads done at p1-end barrier);
        //     16 MFMAs; stage A(t+2) + vmcnt(6).
        RD_A(1);
        if (t + 2 < NT) STGB(t + 2);
        CLOB; BARR; SB0; MM(1, 1); MM(1, 0);
        if (t + 2 < NT) { STGA(t + 2); VMW6; }
        else if (t + 1 < NT) { VMW0; }
        CLOB; BARR;
    }
    #undef STG_HALF
    #undef STGA
    #undef STGB
    #undef RD_A
    #undef RD_B
    #undef MM

    #pragma unroll
    for (int mi = 0; mi < 4; ++mi) {
        int rbase = m0 + wm * 64 + mi * 16 + quad * 4;
        #pragma unroll
        for (int ni = 0; ni < 4; ++ni) {
            int cc = n0 + wn * 64 + ni * 16 + col;
            #pragma unroll
            for (int r = 0; r < 4; ++r)
                C[(long)(rbase + r) * ldc + cc] = (OutT)acc[mi][ni][r];
        }
    }
}

// ---------------- MFMA flash attention, v10 (R12 + fast exp2) -------------
#define QS 72
#define C_SL 0.18033688011112042f   // 0.125 * log2(e)

__device__ __forceinline__ int vsw(int d, int k) {
    return d * 64 + ((((k >> 3) ^ (d & 7) ^ ((d >> 3) & 7)) & 7) << 3) + (k & 7);
}

__global__ __launch_bounds__(256)
void attn_mfma(bf16* __restrict__ qkv)
{
    __shared__ bf16 Ks[64 * QS];        //  9.2 KB
    __shared__ bf16 Vt[64 * 64];        //  8.0 KB (vsw-swizzled)
    __shared__ bf16 Ps[4 * 32 * QS];    // 18.4 KB
    const int T = 2048, D3 = 3072;
    int tid = threadIdx.x;
    int lane = tid & 63, wid = tid >> 6;
    int quad = lane >> 4, col = lane & 15;
    int bh = blockIdx.x & 63;
    int qt = 15 - (blockIdx.x >> 6);     // heavy tiles dispatched first
    int b = bh >> 4, h = bh & 15;
    long base = (long)b * T * D3 + h * 64;
    int q0 = qt * 128;
    int nk = 2 * qt + 2;
    int srow = tid >> 2, dseg = (tid & 3) * 16;   // K staging map (64x64)
    int kg4 = (tid >> 4) * 4, dg4 = (tid & 15) * 4; // V staging map (4k x 4d)
    bf16* Pw = &Ps[wid * 32 * QS];

    // Q B-frags (held in regs): lane holds Q[q=nt*16+col][d=quad*8+j+32*ch]
    bf16x8 aq[2][2];
    #pragma unroll
    for (int nt = 0; nt < 2; ++nt) {
        const bf16* gq = &qkv[base + (long)(q0 + wid * 32 + nt * 16 + col) * D3 + quad * 8];
        aq[nt][0] = *(const bf16x8*)gq;
        aq[nt][1] = *(const bf16x8*)(gq + 32);
    }
    bf16 one1 = (bf16)1.0f;
    bf16x8 bones = {one1, one1, one1, one1, one1, one1, one1, one1};

    f4 of[2][4], lac[2];
    #pragma unroll
    for (int mg = 0; mg < 2; ++mg) {
        lac[mg] = (f4){0.f, 0.f, 0.f, 0.f};
        #pragma unroll
        for (int n = 0; n < 4; ++n) of[mg][n] = (f4){0.f, 0.f, 0.f, 0.f};
    }

    // prefetch k-tile 0
    const bf16* g0 = &qkv[base + (long)srow * D3 + 1024 + dseg];
    bf16x8 kr0 = *(const bf16x8*)g0;
    bf16x8 kr1 = *(const bf16x8*)(g0 + 8);
    const bf16* gV = &qkv[base + (long)kg4 * D3 + 2048 + dg4];
    bf16x4 vr[4];
    #pragma unroll
    for (int j = 0; j < 4; ++j) vr[j] = *(const bf16x4*)(gV + (long)j * D3);

    for (int kt = 0; kt < nk; ++kt) {
        __syncthreads();                 // prior iter's LDS reads done
        *(bf16x8*)&Ks[srow * QS + dseg]     = kr0;
        *(bf16x8*)&Ks[srow * QS + dseg + 8] = kr1;
        #pragma unroll
        for (int i = 0; i < 4; ++i) {    // 4x4 in-register transpose
            bf16x4 c = { vr[0][i], vr[1][i], vr[2][i], vr[3][i] };
            *(bf16x4*)&Vt[vsw(dg4 + i, kg4)] = c;
        }
        if (kt + 1 < nk) {               // latency hidden behind compute
            const bf16* gKn = &qkv[base + (long)((kt + 1) * 64 + srow) * D3 + 1024 + dseg];
            kr0 = *(const bf16x8*)gKn;
            kr1 = *(const bf16x8*)(gKn + 8);
            const bf16* gVn = &qkv[base + (long)((kt + 1) * 64 + kg4) * D3 + 2048 + dg4];
            #pragma unroll
            for (int j = 0; j < 4; ++j) vr[j] = *(const bf16x4*)(gVn + (long)j * D3);
        }
        __syncthreads();
        // S^T = K Q^T, fused per 16-row k-chunk (bounds live registers)
        bool diag = (kt >= nk - 2);
        int k0 = kt * 64;
        #pragma unroll
        for (int mt = 0; mt < 4; ++mt) {
            bf16x8 ak0 = *(const bf16x8*)&Ks[(mt * 16 + col) * QS + quad * 8];
            bf16x8 ak1 = *(const bf16x8*)&Ks[(mt * 16 + col) * QS + 32 + quad * 8];
            #pragma unroll
            for (int nt = 0; nt < 2; ++nt) {
                f4 z = (f4){0.f, 0.f, 0.f, 0.f};
                __builtin_amdgcn_s_setprio(1);
                z = __builtin_amdgcn_mfma_f32_16x16x32_bf16(ak0, aq[nt][0], z, 0, 0, 0);
                f4 st = __builtin_amdgcn_mfma_f32_16x16x32_bf16(ak1, aq[nt][1], z, 0, 0, 0);
                __builtin_amdgcn_s_setprio(0);
                bf16x4 pk;
                if (diag) {
                    int qg = q0 + wid * 32 + nt * 16 + col;
                    #pragma unroll
                    for (int r = 0; r < 4; ++r) {
                        float arg = fmaf(st[r], C_SL, -16.f);
                        if ((k0 + mt * 16 + quad * 4 + r) > qg) arg = -1e30f;
                        pk[r] = (bf16)fast_exp2(arg);
                    }
                } else {
                    #pragma unroll
                    for (int r = 0; r < 4; ++r)
                        pk[r] = (bf16)fast_exp2(fmaf(st[r], C_SL, -16.f));
                }
                *(bf16x4*)&Pw[(nt * 16 + col) * QS + mt * 16 + quad * 4] = pk;
            }
        }
        // P readback (wave-private, no barrier): hoisted A-frags
        bf16x8 ap[2][2];
        #pragma unroll
        for (int mg = 0; mg < 2; ++mg) {
            ap[mg][0] = *(const bf16x8*)&Pw[(mg * 16 + col) * QS + quad * 8];
            ap[mg][1] = *(const bf16x8*)&Pw[(mg * 16 + col) * QS + 32 + quad * 8];
        }
        // O += P V: nd-major so each V frag pair is read ONCE (8 b128/iter)
        #pragma unroll
        for (int nd = 0; nd < 4; ++nd) {
            bf16x8 bv0 = *(const bf16x8*)&Vt[vsw(nd * 16 + col, quad * 8)];
            bf16x8 bv1 = *(const bf16x8*)&Vt[vsw(nd * 16 + col, 32 + quad * 8)];
            __builtin_amdgcn_s_setprio(1);
            of[0][nd] = __builtin_amdgcn_mfma_f32_16x16x32_bf16(ap[0][0], bv0, of[0][nd], 0, 0, 0);
            of[0][nd] = __builtin_amdgcn_mfma_f32_16x16x32_bf16(ap[0][1], bv1, of[0][nd], 0, 0, 0);
            of[1][nd] = __builtin_amdgcn_mfma_f32_16x16x32_bf16(ap[1][0], bv0, of[1][nd], 0, 0, 0);
            of[1][nd] = __builtin_amdgcn_mfma_f32_16x16x32_bf16(ap[1][1], bv1, of[1][nd], 0, 0, 0);
            __builtin_amdgcn_s_setprio(0);
        }
        // l += P 1
        __builtin_amdgcn_s_setprio(1);
        #pragma unroll
        for (int mg = 0; mg < 2; ++mg) {
            lac[mg] = __builtin_amdgcn_mfma_f32_16x16x32_bf16(ap[mg][0], bones, lac[mg], 0, 0, 0);
            lac[mg] = __builtin_amdgcn_mfma_f32_16x16x32_bf16(ap[mg][1], bones, lac[mg], 0, 0, 0);
        }
        __builtin_amdgcn_s_setprio(0);
    }
    // epilogue: y into this block's dead Q region; l is in O's C-layout
    #pragma unroll
    for (int mg = 0; mg < 2; ++mg)
        #pragma unroll
        for (int r = 0; r < 4; ++r) {
            float inv = 1.f / lac[mg][r];
            long yoff = base + (long)(q0 + wid * 32 + mg * 16 + quad * 4 + r) * D3;
            #pragma unroll
            for (int nd = 0; nd < 4; ++nd)
                qkv[yoff + nd * 16 + col] = (bf16)(of[mg][nd][r] * inv);
        }
}

// --------------------------------------------------------------------------
extern "C" void kernel_launch(void* const* d_in, const int* in_sizes, int n_in,
                              void* d_out, int out_size, void* d_ws, size_t ws_size,
                              hipStream_t stream) {
    const float* x      = (const float*)d_in[0];  // [8192,1024] fp32
    const float* W_attn = (const float*)d_in[1];  // [1024,3072] fp32
    const float* W_proj = (const float*)d_in[2];  // [1024,1024] fp32
    float* out = (float*)d_out;                   // [8192,1024] fp32

    // ws layout (58.7 MB): qkv | WtA | WtP
    bf16* qkv = (bf16*)d_ws;                         // [8192,3072]  50.3 MB
    bf16* WtA = qkv + (size_t)8192 * 3072;           // [3072,1024]   6.3 MB
    bf16* WtP = WtA + (size_t)3072 * 1024;           // [1024,1024]   2.1 MB
    bf16* xb = (bf16*)d_out;   // bf16 x staged in d_out; dead before gemm2

    static bool attr_set = false;
    if (!attr_set) {
        hipFuncSetAttribute((const void*)gemm256<bf16>,
                            hipFuncAttributeMaxDynamicSharedMemorySize, 98304);
        hipFuncSetAttribute((const void*)gemm256<float>,
                            hipFuncAttributeMaxDynamicSharedMemorySize, 98304);
        attr_set = true;
    }

    // fused prep: cast x (8192 blocks) + transpose W_attn (768) + W_proj (256)
    prep<<<9216, 256, 0, stream>>>(x, xb, W_attn, WtA, W_proj, WtP);
    // qkv = xb @ W_attn  (bf16 out): 128x256 tiles, grid 12x64 = 768 = 3*256
    gemm256<bf16><<<dim3(12, 64), 512, 98304, stream>>>(xb, WtA, qkv,
                                                        1024, 1024, 3072, 1024);
    // MFMA flash attention; y written into qkv's Q columns
    attn_mfma<<<1024, 256, 0, stream>>>(qkv);
    // out = y @ W_proj: 128x256 tiles, grid 4x64 = 256 = exactly 1 wave
    gemm256<float><<<dim3(4, 64), 512, 98304, stream>>>(qkv, WtP, out,
                                                        3072, 1024, 1024, 1024);
}